// Round 1
// baseline (280.190 us; speedup 1.0000x reference)
//
#include <hip/hip_runtime.h>

#define ALPHA_C 0.9f
#define EPS_C 1e-3f

typedef unsigned short u16;
typedef __attribute__((ext_vector_type(8))) short short8;
typedef __attribute__((ext_vector_type(4))) float f32x4;
#define MFMA(a, b, c) __builtin_amdgcn_mfma_f32_16x16x32_bf16(a, b, c, 0, 0, 0)
// compiler-only ordering fence: LDS write->read hazards here are wave-private
// (HW processes a wave's DS ops in order); we only need to stop compiler reordering.
#define LDS_FENCE() asm volatile("" ::: "memory")

__device__ __forceinline__ u16 f2bf(float f) {
  union { float f; unsigned u; } v; v.f = f;
  unsigned u = v.u;
  u += 0x7FFFu + ((u >> 16) & 1u);
  return (u16)(u >> 16);
}
__device__ __forceinline__ float bf2f(u16 h) {
  union { unsigned u; float f; } v; v.u = ((unsigned)h) << 16;
  return v.f;
}

// ---------------------------------------------------------------------------
// K0: weight conversion fp32 -> bf16 (natural + transposed copies)
__global__ __launch_bounds__(256) void k_conv(
    const float* __restrict__ W1, const float* __restrict__ W2, const float* __restrict__ W3,
    const float* __restrict__ V1, const float* __restrict__ V2,
    u16* __restrict__ W1T, u16* __restrict__ W1n, u16* __restrict__ W2T, u16* __restrict__ W2n,
    u16* __restrict__ W3T, u16* __restrict__ W3n, u16* __restrict__ V1T, u16* __restrict__ V1n,
    u16* __restrict__ V2T, u16* __restrict__ V2n) {
  int i = blockIdx.x * 256 + threadIdx.x;   // 0..32767
  { float v = W1[i]; int k = i >> 6, j = i & 63; u16 b = f2bf(v); W1n[i] = b; W1T[j * 512 + k] = b; }
  { float v = V1[i]; int k = i >> 6, j = i & 63; u16 b = f2bf(v); V1n[i] = b; V1T[j * 512 + k] = b; }
  { float v = W3[i]; int k = i >> 9, n = i & 511; u16 b = f2bf(v); W3n[i] = b; W3T[n * 64 + k] = b; }
  if (i < 4096) {
    { float v = W2[i]; int k = i >> 6, j = i & 63; u16 b = f2bf(v); W2n[i] = b; W2T[j * 64 + k] = b; }
    { float v = V2[i]; int k = i >> 6, j = i & 63; u16 b = f2bf(v); V2n[i] = b; V2T[j * 64 + k] = b; }
  }
}

// ---------------------------------------------------------------------------
// K1 (fused): H1,H2 (fwd MLP) -> F -> G1,g2,lyap -> s3,s2 -> U,T3,T2 -> GV ssq,
// NUM, denom partials.  All activations stay in LDS; every B operand is
// fragment-loaded directly from global (K-contiguous layouts).  All LDS
// transposes are wave-private 16-row strips -> no __syncthreads in the body.
__global__ __launch_bounds__(256) void k_fused(
    const float* __restrict__ x,
    const u16* __restrict__ W1T, const float* __restrict__ b1,
    const u16* __restrict__ W2T, const float* __restrict__ b2,
    const u16* __restrict__ W3T, const float* __restrict__ b3,
    const u16* __restrict__ V1T, const float* __restrict__ c1,
    const u16* __restrict__ V2T, const u16* __restrict__ V2n, const float* __restrict__ c2,
    const float* __restrict__ V3, const float* __restrict__ c3,
    const u16* __restrict__ V1n, const u16* __restrict__ W3n,
    const u16* __restrict__ W2n, const u16* __restrict__ W1n,
    u16* __restrict__ Fb, u16* __restrict__ T2b,
    float* __restrict__ NUM, float* __restrict__ DP) {
  __shared__ u16 H1s[64 * 72];   // H1 bf16, later overwritten by T2
  __shared__ u16 H2s[64 * 72];   // H2 bf16, later overwritten by masked T3
  __shared__ u16 S2s[64 * 72];   // G1 -> s3 -> S2 (same stride, wave-private rows)
  __shared__ u16 As[64 * 136];   // F chunk (phase B) / U chunk (phase C)
  __shared__ float dred[4];
  const int tid = threadIdx.x;
  const int lane = tid & 63, w = tid >> 6, q = lane >> 4, r = lane & 15;
  const int m0 = blockIdx.x * 64;
  const int arow = w * 16 + r;        // A-fragment row owned by this lane

  // ---- phase A1: H1 = relu(x @ W1 + b1), K = 512, direct f32 loads + convert
  f32x4 acc1[4] = {};
  #pragma unroll 4
  for (int ks = 0; ks < 16; ++ks) {
    const float4 v0 = *(const float4*)&x[(size_t)(m0 + arow) * 512 + ks * 32 + q * 8];
    const float4 v1 = *(const float4*)&x[(size_t)(m0 + arow) * 512 + ks * 32 + q * 8 + 4];
    short8 a;
    a[0] = (short)f2bf(v0.x); a[1] = (short)f2bf(v0.y);
    a[2] = (short)f2bf(v0.z); a[3] = (short)f2bf(v0.w);
    a[4] = (short)f2bf(v1.x); a[5] = (short)f2bf(v1.y);
    a[6] = (short)f2bf(v1.z); a[7] = (short)f2bf(v1.w);
    #pragma unroll
    for (int t = 0; t < 4; ++t) {
      short8 b = *(const short8*)&W1T[(t * 16 + r) * 512 + ks * 32 + q * 8];
      acc1[t] = MFMA(a, b, acc1[t]);
    }
  }
  #pragma unroll
  for (int t = 0; t < 4; ++t) {
    int col = t * 16 + r; float bv = b1[col];
    #pragma unroll
    for (int g = 0; g < 4; ++g) {
      float h = acc1[t][g] + bv; h = h > 0.f ? h : 0.f;
      H1s[(w * 16 + q * 4 + g) * 72 + col] = f2bf(h);
    }
  }
  LDS_FENCE();

  // ---- phase A2: H2 = relu(H1 @ W2 + b2), K = 64
  f32x4 acc2[4] = {};
  #pragma unroll
  for (int ks = 0; ks < 2; ++ks) {
    short8 a = *(const short8*)&H1s[arow * 72 + ks * 32 + q * 8];
    #pragma unroll
    for (int t = 0; t < 4; ++t) {
      short8 b = *(const short8*)&W2T[(t * 16 + r) * 64 + ks * 32 + q * 8];
      acc2[t] = MFMA(a, b, acc2[t]);
    }
  }
  #pragma unroll
  for (int t = 0; t < 4; ++t) {
    int col = t * 16 + r; float bv = b2[col];
    #pragma unroll
    for (int g = 0; g < 4; ++g) {
      float h = acc2[t][g] + bv; h = h > 0.f ? h : 0.f;
      H2s[(w * 16 + q * 4 + g) * 72 + col] = f2bf(h);
    }
  }
  LDS_FENCE();

  // ---- phase B: F = H2 @ W3 + b3 (store bf16 to Fb), G1 accum = relu-input F @ V1
  f32x4 g1acc[4] = {};
  float ssq[4] = {0.f, 0.f, 0.f, 0.f};
  #pragma unroll 1
  for (int nc = 0; nc < 4; ++nc) {
    f32x4 facc[8] = {};
    #pragma unroll
    for (int ks = 0; ks < 2; ++ks) {
      short8 a = *(const short8*)&H2s[arow * 72 + ks * 32 + q * 8];
      #pragma unroll
      for (int t = 0; t < 8; ++t) {
        short8 b = *(const short8*)&W3T[(nc * 128 + t * 16 + r) * 64 + ks * 32 + q * 8];
        facc[t] = MFMA(a, b, facc[t]);
      }
    }
    #pragma unroll
    for (int t = 0; t < 8; ++t) {
      int colg = nc * 128 + t * 16 + r;
      float bv = b3[colg];
      #pragma unroll
      for (int g = 0; g < 4; ++g) {
        float v = facc[t][g] + bv;
        ssq[g] += v * v;
        u16 bb = f2bf(v);
        As[(w * 16 + q * 4 + g) * 136 + t * 16 + r] = bb;
        Fb[(size_t)(m0 + w * 16 + q * 4 + g) * 512 + colg] = bb;   // L2 write-combines
      }
    }
    LDS_FENCE();
    #pragma unroll
    for (int ks = 0; ks < 4; ++ks) {
      short8 a = *(const short8*)&As[arow * 136 + ks * 32 + q * 8];
      #pragma unroll
      for (int t = 0; t < 4; ++t) {
        short8 b = *(const short8*)&V1T[(t * 16 + r) * 512 + nc * 128 + ks * 32 + q * 8];
        g1acc[t] = MFMA(a, b, g1acc[t]);
      }
    }
  }

  // G1 = relu(g1acc + c1) -> S2s
  f32x4 g1v[4];
  #pragma unroll
  for (int t = 0; t < 4; ++t) {
    int col = t * 16 + r; float cv = c1[col];
    #pragma unroll
    for (int g = 0; g < 4; ++g) {
      float v = g1acc[t][g] + cv; v = v > 0.f ? v : 0.f;
      g1v[t][g] = v;
      S2s[(w * 16 + q * 4 + g) * 72 + col] = f2bf(v);
    }
  }
  LDS_FENCE();
  // g2 = G1 @ V2T
  f32x4 g2acc[4] = {};
  #pragma unroll
  for (int ks = 0; ks < 2; ++ks) {
    short8 a = *(const short8*)&S2s[arow * 72 + ks * 32 + q * 8];
    #pragma unroll
    for (int t = 0; t < 4; ++t) {
      short8 b = *(const short8*)&V2T[(t * 16 + r) * 64 + ks * 32 + q * 8];
      g2acc[t] = MFMA(a, b, g2acc[t]);
    }
  }
  // s3 = (g2pre>0)*V3 -> S2s (same rows, after own reads); lyap partial
  float tot[4] = {0.f, 0.f, 0.f, 0.f};
  #pragma unroll
  for (int t = 0; t < 4; ++t) {
    int col = t * 16 + r;
    float c2v = c2[col], v3v = V3[col];
    #pragma unroll
    for (int g = 0; g < 4; ++g) {
      float pre = g2acc[t][g] + c2v;
      float g2 = pre > 0.f ? pre : 0.f;
      S2s[(w * 16 + q * 4 + g) * 72 + col] = pre > 0.f ? f2bf(v3v) : (u16)0;
      tot[g] += g2 * v3v;
    }
  }
  LDS_FENCE();
  // s2 = s3 @ V2 (natural), masked by G1>0 -> S2s
  f32x4 s2acc[4] = {};
  #pragma unroll
  for (int ks = 0; ks < 2; ++ks) {
    short8 a = *(const short8*)&S2s[arow * 72 + ks * 32 + q * 8];
    #pragma unroll
    for (int t = 0; t < 4; ++t) {
      short8 b = *(const short8*)&V2n[(t * 16 + r) * 64 + ks * 32 + q * 8];
      s2acc[t] = MFMA(a, b, s2acc[t]);
    }
  }
  #pragma unroll
  for (int t = 0; t < 4; ++t) {
    int col = t * 16 + r;
    #pragma unroll
    for (int g = 0; g < 4; ++g) {
      float sv = g1v[t][g] > 0.f ? s2acc[t][g] : 0.f;
      S2s[(w * 16 + q * 4 + g) * 72 + col] = f2bf(sv);
    }
  }
  LDS_FENCE();
  // lyap per row, kept in registers (all lanes of the r-group hold it)
  float c3v = c3[0];
  float lyap_row[4];
  #pragma unroll
  for (int g = 0; g < 4; ++g) {
    float s = tot[g] + EPS_C * ssq[g];
    s += __shfl_xor(s, 1); s += __shfl_xor(s, 2); s += __shfl_xor(s, 4); s += __shfl_xor(s, 8);
    lyap_row[g] = s + c3v;
  }

  // ensure all Fb stores have landed in L2 before same-wave re-reads below
  asm volatile("s_waitcnt vmcnt(0)" ::: "memory");

  // ---- phase C: U = s2 @ V1^T + 2eps*F ; T3 = (U W3^T)*(H2>0) ; T2 = (T3 W2^T)*(H1>0)
  f32x4 t3acc[4] = {};
  #pragma unroll 1
  for (int nc = 0; nc < 4; ++nc) {
    f32x4 uacc[8] = {};
    #pragma unroll
    for (int ks = 0; ks < 2; ++ks) {
      short8 a = *(const short8*)&S2s[arow * 72 + ks * 32 + q * 8];
      #pragma unroll
      for (int t = 0; t < 8; ++t) {
        short8 b = *(const short8*)&V1n[(nc * 128 + t * 16 + r) * 64 + ks * 32 + q * 8];
        uacc[t] = MFMA(a, b, uacc[t]);
      }
    }
    #pragma unroll
    for (int t = 0; t < 8; ++t) {
      #pragma unroll
      for (int g = 0; g < 4; ++g) {
        int rl = w * 16 + q * 4 + g;
        float f = bf2f(Fb[(size_t)(m0 + rl) * 512 + nc * 128 + t * 16 + r]);
        As[rl * 136 + t * 16 + r] = f2bf(uacc[t][g] + 2.f * EPS_C * f);
      }
    }
    LDS_FENCE();
    #pragma unroll
    for (int ks = 0; ks < 4; ++ks) {
      short8 a = *(const short8*)&As[arow * 136 + ks * 32 + q * 8];
      #pragma unroll
      for (int t = 0; t < 4; ++t) {
        short8 b = *(const short8*)&W3n[(size_t)(t * 16 + r) * 512 + nc * 128 + ks * 32 + q * 8];
        t3acc[t] = MFMA(a, b, t3acc[t]);
      }
    }
  }
  // T3 masked by H2>0 -> overwrite H2s (same lane, same address)
  #pragma unroll
  for (int t = 0; t < 4; ++t) {
    int col = t * 16 + r;
    #pragma unroll
    for (int g = 0; g < 4; ++g) {
      int addr = (w * 16 + q * 4 + g) * 72 + col;
      u16 h2 = H2s[addr];
      H2s[addr] = h2 ? f2bf(t3acc[t][g]) : (u16)0;
    }
  }
  LDS_FENCE();
  // T2 = T3 @ W2 (natural), masked by H1>0 -> H1s + global T2b
  f32x4 t2acc[4] = {};
  #pragma unroll
  for (int ks = 0; ks < 2; ++ks) {
    short8 a = *(const short8*)&H2s[arow * 72 + ks * 32 + q * 8];
    #pragma unroll
    for (int t = 0; t < 4; ++t) {
      short8 b = *(const short8*)&W2n[(t * 16 + r) * 64 + ks * 32 + q * 8];
      t2acc[t] = MFMA(a, b, t2acc[t]);
    }
  }
  #pragma unroll
  for (int t = 0; t < 4; ++t) {
    int col = t * 16 + r;
    #pragma unroll
    for (int g = 0; g < 4; ++g) {
      int rl = w * 16 + q * 4 + g;
      int addr = rl * 72 + col;
      u16 h1 = H1s[addr];
      u16 tv = h1 ? f2bf(t2acc[t][g]) : (u16)0;
      H1s[addr] = tv;
      T2b[(size_t)(m0 + rl) * 64 + col] = tv;
    }
  }
  LDS_FENCE();
  // GV = T2 @ W1^T, ssq2 = row norms (GV itself recomputed in k_out)
  float ssq2[4] = {0.f, 0.f, 0.f, 0.f};
  #pragma unroll 1
  for (int nc = 0; nc < 4; ++nc) {
    f32x4 acc[8] = {};
    #pragma unroll
    for (int ks = 0; ks < 2; ++ks) {
      short8 a = *(const short8*)&H1s[arow * 72 + ks * 32 + q * 8];
      #pragma unroll
      for (int t = 0; t < 8; ++t) {
        short8 b = *(const short8*)&W1n[(nc * 128 + t * 16 + r) * 64 + ks * 32 + q * 8];
        acc[t] = MFMA(a, b, acc[t]);
      }
    }
    #pragma unroll
    for (int t = 0; t < 8; ++t)
      #pragma unroll
      for (int g = 0; g < 4; ++g) ssq2[g] += acc[t][g] * acc[t][g];
  }
  float totw = 0.f;
  #pragma unroll
  for (int g = 0; g < 4; ++g) {
    float s = ssq2[g];
    s += __shfl_xor(s, 1); s += __shfl_xor(s, 2); s += __shfl_xor(s, 4); s += __shfl_xor(s, 8);
    if (r == 0) {
      int rowg = m0 + w * 16 + q * 4 + g;
      float nm = s + ALPHA_C * lyap_row[g];
      NUM[rowg] = nm > 0.f ? nm : 0.f;
    }
    s += __shfl_xor(s, 16); s += __shfl_xor(s, 32);
    totw += s;
  }
  if (lane == 0) dred[w] = totw;
  __syncthreads();
  if (tid == 0) atomicAdd(&DP[blockIdx.x & 255], dred[0] + dred[1] + dred[2] + dred[3]);
}

// ---------------------------------------------------------------------------
// K2: recompute GV from T2 (direct fragment loads); out = F - (num/denom)*GV
__global__ __launch_bounds__(256) void k_out(
    const u16* __restrict__ T2b, const u16* __restrict__ W1n,
    const u16* __restrict__ Fb, const float* __restrict__ NUM, const float* __restrict__ DP,
    float* __restrict__ out) {
  __shared__ float red[256];
  const int tid = threadIdx.x;
  const int lane = tid & 63, w = tid >> 6, q = lane >> 4, r = lane & 15;
  const int m0 = blockIdx.x * 64;
  const int arow = w * 16 + r;
  red[tid] = DP[tid];
  __syncthreads();
  for (int s = 128; s >= 1; s >>= 1) {
    if (tid < s) red[tid] += red[tid + s];
    __syncthreads();
  }
  const float inv_denom = 1.f / red[0];
  float sc[4];
  #pragma unroll
  for (int g = 0; g < 4; ++g) sc[g] = NUM[m0 + w * 16 + q * 4 + g] * inv_denom;
  // T2 A-fragments: loaded once, reused for all 4 nc chunks
  short8 a0 = *(const short8*)&T2b[(size_t)(m0 + arow) * 64 + q * 8];
  short8 a1 = *(const short8*)&T2b[(size_t)(m0 + arow) * 64 + 32 + q * 8];
  #pragma unroll 1
  for (int nc = 0; nc < 4; ++nc) {
    f32x4 acc[8] = {};
    #pragma unroll
    for (int t = 0; t < 8; ++t) {
      short8 b0 = *(const short8*)&W1n[(nc * 128 + t * 16 + r) * 64 + q * 8];
      short8 b1 = *(const short8*)&W1n[(nc * 128 + t * 16 + r) * 64 + 32 + q * 8];
      acc[t] = MFMA(a0, b0, acc[t]);
      acc[t] = MFMA(a1, b1, acc[t]);
    }
    #pragma unroll
    for (int t = 0; t < 8; ++t) {
      int colg = nc * 128 + t * 16 + r;
      #pragma unroll
      for (int g = 0; g < 4; ++g) {
        int rl = w * 16 + q * 4 + g;
        float fv = bf2f(Fb[(size_t)(m0 + rl) * 512 + colg]);
        out[(size_t)(m0 + rl) * 512 + colg] = fv - sc[g] * acc[t][g];
      }
    }
  }
}

// ---------------------------------------------------------------------------
extern "C" void kernel_launch(void* const* d_in, const int* in_sizes, int n_in,
                              void* d_out, int out_size, void* d_ws, size_t ws_size,
                              hipStream_t stream) {
  const float* x  = (const float*)d_in[0];
  const float* W1 = (const float*)d_in[1];
  const float* b1 = (const float*)d_in[2];
  const float* W2 = (const float*)d_in[3];
  const float* b2 = (const float*)d_in[4];
  const float* W3 = (const float*)d_in[5];
  const float* b3 = (const float*)d_in[6];
  const float* V1 = (const float*)d_in[7];
  const float* c1 = (const float*)d_in[8];
  const float* V2 = (const float*)d_in[9];
  const float* c2 = (const float*)d_in[10];
  const float* V3 = (const float*)d_in[11];
  const float* c3 = (const float*)d_in[12];
  float* out = (float*)d_out;

  u16* Fb = (u16*)d_ws;                       // 16777216 u16 = 32 MB
  float* NUM  = (float*)(Fb + 16777216);      // 32768 f
  float* DP   = NUM + 32768;                  // 256 f
  u16* T2b  = (u16*)(DP + 256);               // 2097152 u16
  u16* W1Tb = T2b + 2097152;
  u16* W1nb = W1Tb + 32768;
  u16* W2Tb = W1nb + 32768;
  u16* W2nb = W2Tb + 4096;
  u16* W3Tb = W2nb + 4096;
  u16* W3nb = W3Tb + 32768;
  u16* V1Tb = W3nb + 32768;
  u16* V1nb = V1Tb + 32768;
  u16* V2Tb = V1nb + 32768;
  u16* V2nb = V2Tb + 4096;

  hipMemsetAsync(DP, 0, 256 * sizeof(float), stream);

  k_conv<<<128, 256, 0, stream>>>(W1, W2, W3, V1, V2,
                                  W1Tb, W1nb, W2Tb, W2nb, W3Tb, W3nb, V1Tb, V1nb, V2Tb, V2nb);
  k_fused<<<512, 256, 0, stream>>>(x, W1Tb, b1, W2Tb, b2, W3Tb, b3, V1Tb, c1,
                                   V2Tb, V2nb, c2, V3, c3, V1nb, W3nb, W2nb, W1nb,
                                   Fb, T2b, NUM, DP);
  k_out<<<512, 256, 0, stream>>>(T2b, W1nb, Fb, NUM, DP, out);
}

// Round 2
// 243.268 us; speedup vs baseline: 1.1518x; 1.1518x over previous
//
#include <hip/hip_runtime.h>

#define ALPHA_C 0.9f
#define EPS_C 1e-3f

typedef unsigned short u16;
typedef __attribute__((ext_vector_type(8))) short short8;
typedef __attribute__((ext_vector_type(4))) short short4v;
typedef __attribute__((ext_vector_type(4))) float f32x4;
#define MFMA(a, b, c) __builtin_amdgcn_mfma_f32_16x16x32_bf16(a, b, c, 0, 0, 0)
// compiler-only ordering fence; wave-private LDS hazards are in-order in HW
#define LDS_FENCE() asm volatile("" ::: "memory")

__device__ __forceinline__ u16 f2bf(float f) {
  union { float f; unsigned u; } v; v.f = f;
  unsigned u = v.u;
  u += 0x7FFFu + ((u >> 16) & 1u);
  return (u16)(u >> 16);
}
__device__ __forceinline__ float bf2f(u16 h) {
  union { unsigned u; float f; } v; v.u = ((unsigned)h) << 16;
  return v.f;
}

// ---------------------------------------------------------------------------
// K0: weight conversion fp32 -> bf16, packed in MFMA B-fragment order:
// P[((tile*KS + ks)*4 + q)*16 + r]*8 + e  == 1KB contiguous per (tile,ks) wave load
__global__ __launch_bounds__(256) void k_conv(
    const float* __restrict__ W1, const float* __restrict__ W2, const float* __restrict__ W3,
    const float* __restrict__ V1, const float* __restrict__ V2,
    u16* __restrict__ PW1T, u16* __restrict__ PW1n, u16* __restrict__ PV1T, u16* __restrict__ PV1n,
    u16* __restrict__ PW3T, u16* __restrict__ PW3n, u16* __restrict__ PW2T, u16* __restrict__ PW2n,
    u16* __restrict__ PV2T, u16* __restrict__ PV2n) {
  int i = blockIdx.x * 256 + threadIdx.x;   // 0..32767
  {
    int k = i >> 6, j = i & 63;             // W1[k][j], V1[k][j]  (512x64)
    u16 b = f2bf(W1[i]);
    // W1T view: rows=j (64), K=k (512)
    PW1T[((((j >> 4) * 16 + (k >> 5)) * 4 + ((k & 31) >> 3)) * 16 + (j & 15)) * 8 + (k & 7)] = b;
    // W1n view: rows=k (512), K=j (64)
    PW1n[((((k >> 4) * 2 + (j >> 5)) * 4 + ((j & 31) >> 3)) * 16 + (k & 15)) * 8 + (j & 7)] = b;
    u16 c = f2bf(V1[i]);
    PV1T[((((j >> 4) * 16 + (k >> 5)) * 4 + ((k & 31) >> 3)) * 16 + (j & 15)) * 8 + (k & 7)] = c;
    PV1n[((((k >> 4) * 2 + (j >> 5)) * 4 + ((j & 31) >> 3)) * 16 + (k & 15)) * 8 + (j & 7)] = c;
  }
  {
    int k = i >> 9, n = i & 511;            // W3[k][n] (64x512)
    u16 b = f2bf(W3[i]);
    // W3T view: rows=n (512), K=k (64)
    PW3T[((((n >> 4) * 2 + (k >> 5)) * 4 + ((k & 31) >> 3)) * 16 + (n & 15)) * 8 + (k & 7)] = b;
    // W3n view: rows=k (64), K=n (512)
    PW3n[((((k >> 4) * 16 + (n >> 5)) * 4 + ((n & 31) >> 3)) * 16 + (k & 15)) * 8 + (n & 7)] = b;
  }
  if (i < 4096) {
    int k = i >> 6, j = i & 63;             // W2[k][j], V2[k][j] (64x64)
    u16 b = f2bf(W2[i]);
    PW2T[((((j >> 4) * 2 + (k >> 5)) * 4 + ((k & 31) >> 3)) * 16 + (j & 15)) * 8 + (k & 7)] = b;
    PW2n[((((k >> 4) * 2 + (j >> 5)) * 4 + ((j & 31) >> 3)) * 16 + (k & 15)) * 8 + (j & 7)] = b;
    u16 c = f2bf(V2[i]);
    PV2T[((((j >> 4) * 2 + (k >> 5)) * 4 + ((k & 31) >> 3)) * 16 + (j & 15)) * 8 + (k & 7)] = c;
    PV2n[((((k >> 4) * 2 + (j >> 5)) * 4 + ((j & 31) >> 3)) * 16 + (k & 15)) * 8 + (j & 7)] = c;
  }
}

// ---------------------------------------------------------------------------
__global__ __launch_bounds__(256, 2) void k_fused(
    const float* __restrict__ x,
    const u16* __restrict__ PW1T, const float* __restrict__ b1,
    const u16* __restrict__ PW2T, const float* __restrict__ b2,
    const u16* __restrict__ PW3T, const float* __restrict__ b3,
    const u16* __restrict__ PV1T, const float* __restrict__ c1,
    const u16* __restrict__ PV2T, const u16* __restrict__ PV2n, const float* __restrict__ c2,
    const float* __restrict__ V3, const float* __restrict__ c3,
    const u16* __restrict__ PV1n, const u16* __restrict__ PW3n,
    const u16* __restrict__ PW2n, const u16* __restrict__ PW1n,
    u16* __restrict__ FP, u16* __restrict__ T2P,
    float* __restrict__ NUM, float* __restrict__ DP) {
  __shared__ u16 H1s[64 * 72];
  __shared__ u16 H2s[64 * 72];
  __shared__ u16 S2s[64 * 72];
  __shared__ u16 As[64 * 136];
  __shared__ float dred[4];
  const int tid = threadIdx.x;
  const int lane = tid & 63, w = tid >> 6, q = lane >> 4, r = lane & 15;
  const int m0 = blockIdx.x * 64;
  const int arow = w * 16 + r;
  const int strip = blockIdx.x * 4 + w;
  const int h = lane >> 5, c4 = lane & 31;   // staging coords
  const float* xbase = x + (size_t)(m0 + w * 16) * 512;

  // ---- phase A1: H1 = relu(x @ W1 + b1); x staged per-128-col chunk, dbuf'd
  f32x4 acc1[4] = {};
  float4 xr0[8], xr1[8];

#define LOAD_X(regs, kc)                                                        \
  _Pragma("unroll") for (int it = 0; it < 8; ++it)                              \
    regs[it] = *(const float4*)&xbase[(it * 2 + h) * 512 + (kc) * 128 + c4 * 4];

#define STAGE_X(regs)                                                           \
  _Pragma("unroll") for (int it = 0; it < 8; ++it) {                            \
    float4 v = regs[it];                                                        \
    short4v s4;                                                                 \
    s4[0] = (short)f2bf(v.x); s4[1] = (short)f2bf(v.y);                         \
    s4[2] = (short)f2bf(v.z); s4[3] = (short)f2bf(v.w);                         \
    *(short4v*)&As[(w * 16 + it * 2 + h) * 136 + c4 * 4] = s4;                  \
  }

#define MFMA_X(kc)                                                              \
  _Pragma("unroll") for (int ks = 0; ks < 4; ++ks) {                            \
    short8 a = *(const short8*)&As[arow * 136 + ks * 32 + q * 8];               \
    _Pragma("unroll") for (int t = 0; t < 4; ++t) {                             \
      short8 b = *(const short8*)&PW1T[((t * 16 + (kc) * 4 + ks) * 64 + lane) * 8]; \
      acc1[t] = MFMA(a, b, acc1[t]);                                            \
    }                                                                           \
  }

  LOAD_X(xr0, 0)
  STAGE_X(xr0) LDS_FENCE(); LOAD_X(xr1, 1) MFMA_X(0) LDS_FENCE();
  STAGE_X(xr1) LDS_FENCE(); LOAD_X(xr0, 2) MFMA_X(1) LDS_FENCE();
  STAGE_X(xr0) LDS_FENCE(); LOAD_X(xr1, 3) MFMA_X(2) LDS_FENCE();
  STAGE_X(xr1) LDS_FENCE(); MFMA_X(3)

  #pragma unroll
  for (int t = 0; t < 4; ++t) {
    int col = t * 16 + r; float bv = b1[col];
    #pragma unroll
    for (int g = 0; g < 4; ++g) {
      float hh = acc1[t][g] + bv; hh = hh > 0.f ? hh : 0.f;
      H1s[(w * 16 + q * 4 + g) * 72 + col] = f2bf(hh);
    }
  }
  LDS_FENCE();

  // ---- phase A2: H2 = relu(H1 @ W2 + b2)
  f32x4 acc2[4] = {};
  #pragma unroll
  for (int ks = 0; ks < 2; ++ks) {
    short8 a = *(const short8*)&H1s[arow * 72 + ks * 32 + q * 8];
    #pragma unroll
    for (int t = 0; t < 4; ++t) {
      short8 b = *(const short8*)&PW2T[((t * 2 + ks) * 64 + lane) * 8];
      acc2[t] = MFMA(a, b, acc2[t]);
    }
  }
  #pragma unroll
  for (int t = 0; t < 4; ++t) {
    int col = t * 16 + r; float bv = b2[col];
    #pragma unroll
    for (int g = 0; g < 4; ++g) {
      float hh = acc2[t][g] + bv; hh = hh > 0.f ? hh : 0.f;
      H2s[(w * 16 + q * 4 + g) * 72 + col] = f2bf(hh);
    }
  }
  LDS_FENCE();

  // ---- phase B: F = H2 @ W3 + b3 (regs + packed store), G1 accum = F @ V1
  f32x4 g1acc[4] = {};
  float ssq[4] = {0.f, 0.f, 0.f, 0.f};
  unsigned fpk[4][8][2];
  #pragma unroll
  for (int nc = 0; nc < 4; ++nc) {
    f32x4 facc[8] = {};
    #pragma unroll
    for (int ks = 0; ks < 2; ++ks) {
      short8 a = *(const short8*)&H2s[arow * 72 + ks * 32 + q * 8];
      #pragma unroll
      for (int t = 0; t < 8; ++t) {
        short8 b = *(const short8*)&PW3T[(((nc * 8 + t) * 2 + ks) * 64 + lane) * 8];
        facc[t] = MFMA(a, b, facc[t]);
      }
    }
    #pragma unroll
    for (int t = 0; t < 8; ++t) {
      float bv = b3[nc * 128 + t * 16 + r];
      u16 bb0, bb1, bb2, bb3;
      {
        float v = facc[t][0] + bv; ssq[0] += v * v; bb0 = f2bf(v);
        As[(w * 16 + q * 4 + 0) * 136 + t * 16 + r] = bb0;
      }
      {
        float v = facc[t][1] + bv; ssq[1] += v * v; bb1 = f2bf(v);
        As[(w * 16 + q * 4 + 1) * 136 + t * 16 + r] = bb1;
      }
      {
        float v = facc[t][2] + bv; ssq[2] += v * v; bb2 = f2bf(v);
        As[(w * 16 + q * 4 + 2) * 136 + t * 16 + r] = bb2;
      }
      {
        float v = facc[t][3] + bv; ssq[3] += v * v; bb3 = f2bf(v);
        As[(w * 16 + q * 4 + 3) * 136 + t * 16 + r] = bb3;
      }
      fpk[nc][t][0] = (unsigned)bb0 | ((unsigned)bb1 << 16);
      fpk[nc][t][1] = (unsigned)bb2 | ((unsigned)bb3 << 16);
      short4v s4; s4[0] = (short)bb0; s4[1] = (short)bb1; s4[2] = (short)bb2; s4[3] = (short)bb3;
      *(short4v*)&FP[(size_t)(((strip * 4 + nc) * 8 + t) * 64 + lane) * 4] = s4;
    }
    LDS_FENCE();
    #pragma unroll
    for (int ks = 0; ks < 4; ++ks) {
      short8 a = *(const short8*)&As[arow * 136 + ks * 32 + q * 8];
      #pragma unroll
      for (int t = 0; t < 4; ++t) {
        short8 b = *(const short8*)&PV1T[((t * 16 + nc * 4 + ks) * 64 + lane) * 8];
        g1acc[t] = MFMA(a, b, g1acc[t]);
      }
    }
    LDS_FENCE();
  }

  // G1 = relu(g1acc + c1) -> S2s
  f32x4 g1v[4];
  #pragma unroll
  for (int t = 0; t < 4; ++t) {
    int col = t * 16 + r; float cv = c1[col];
    #pragma unroll
    for (int g = 0; g < 4; ++g) {
      float v = g1acc[t][g] + cv; v = v > 0.f ? v : 0.f;
      g1v[t][g] = v;
      S2s[(w * 16 + q * 4 + g) * 72 + col] = f2bf(v);
    }
  }
  LDS_FENCE();
  // g2 = G1 @ V2T
  f32x4 g2acc[4] = {};
  #pragma unroll
  for (int ks = 0; ks < 2; ++ks) {
    short8 a = *(const short8*)&S2s[arow * 72 + ks * 32 + q * 8];
    #pragma unroll
    for (int t = 0; t < 4; ++t) {
      short8 b = *(const short8*)&PV2T[((t * 2 + ks) * 64 + lane) * 8];
      g2acc[t] = MFMA(a, b, g2acc[t]);
    }
  }
  // s3 = (g2pre>0)*V3 -> S2s; lyap partial
  float tot[4] = {0.f, 0.f, 0.f, 0.f};
  #pragma unroll
  for (int t = 0; t < 4; ++t) {
    int col = t * 16 + r;
    float c2v = c2[col], v3v = V3[col];
    #pragma unroll
    for (int g = 0; g < 4; ++g) {
      float pre = g2acc[t][g] + c2v;
      float g2 = pre > 0.f ? pre : 0.f;
      S2s[(w * 16 + q * 4 + g) * 72 + col] = pre > 0.f ? f2bf(v3v) : (u16)0;
      tot[g] += g2 * v3v;
    }
  }
  LDS_FENCE();
  // s2 = s3 @ V2 (natural), masked by G1>0 -> S2s
  f32x4 s2acc[4] = {};
  #pragma unroll
  for (int ks = 0; ks < 2; ++ks) {
    short8 a = *(const short8*)&S2s[arow * 72 + ks * 32 + q * 8];
    #pragma unroll
    for (int t = 0; t < 4; ++t) {
      short8 b = *(const short8*)&PV2n[((t * 2 + ks) * 64 + lane) * 8];
      s2acc[t] = MFMA(a, b, s2acc[t]);
    }
  }
  #pragma unroll
  for (int t = 0; t < 4; ++t) {
    int col = t * 16 + r;
    #pragma unroll
    for (int g = 0; g < 4; ++g) {
      float sv = g1v[t][g] > 0.f ? s2acc[t][g] : 0.f;
      S2s[(w * 16 + q * 4 + g) * 72 + col] = f2bf(sv);
    }
  }
  LDS_FENCE();
  float c3v = c3[0];
  float lyap_row[4];
  #pragma unroll
  for (int g = 0; g < 4; ++g) {
    float s = tot[g] + EPS_C * ssq[g];
    s += __shfl_xor(s, 1); s += __shfl_xor(s, 2); s += __shfl_xor(s, 4); s += __shfl_xor(s, 8);
    lyap_row[g] = s + c3v;
  }

  // ---- phase C: U = s2 @ V1^T + 2eps*F (F from regs); T3 = (U W3^T)*(H2>0)
  f32x4 t3acc[4] = {};
  #pragma unroll
  for (int nc = 0; nc < 4; ++nc) {
    f32x4 uacc[8] = {};
    #pragma unroll
    for (int ks = 0; ks < 2; ++ks) {
      short8 a = *(const short8*)&S2s[arow * 72 + ks * 32 + q * 8];
      #pragma unroll
      for (int t = 0; t < 8; ++t) {
        short8 b = *(const short8*)&PV1n[(((nc * 8 + t) * 2 + ks) * 64 + lane) * 8];
        uacc[t] = MFMA(a, b, uacc[t]);
      }
    }
    #pragma unroll
    for (int t = 0; t < 8; ++t) {
      float f0 = bf2f((u16)(fpk[nc][t][0] & 0xFFFFu));
      float f1 = bf2f((u16)(fpk[nc][t][0] >> 16));
      float f2 = bf2f((u16)(fpk[nc][t][1] & 0xFFFFu));
      float f3 = bf2f((u16)(fpk[nc][t][1] >> 16));
      As[(w * 16 + q * 4 + 0) * 136 + t * 16 + r] = f2bf(uacc[t][0] + 2.f * EPS_C * f0);
      As[(w * 16 + q * 4 + 1) * 136 + t * 16 + r] = f2bf(uacc[t][1] + 2.f * EPS_C * f1);
      As[(w * 16 + q * 4 + 2) * 136 + t * 16 + r] = f2bf(uacc[t][2] + 2.f * EPS_C * f2);
      As[(w * 16 + q * 4 + 3) * 136 + t * 16 + r] = f2bf(uacc[t][3] + 2.f * EPS_C * f3);
    }
    LDS_FENCE();
    #pragma unroll
    for (int ks = 0; ks < 4; ++ks) {
      short8 a = *(const short8*)&As[arow * 136 + ks * 32 + q * 8];
      #pragma unroll
      for (int t = 0; t < 4; ++t) {
        short8 b = *(const short8*)&PW3n[((t * 16 + nc * 4 + ks) * 64 + lane) * 8];
        t3acc[t] = MFMA(a, b, t3acc[t]);
      }
    }
    LDS_FENCE();
  }
  // T3 masked by H2>0 -> H2s
  #pragma unroll
  for (int t = 0; t < 4; ++t) {
    int col = t * 16 + r;
    #pragma unroll
    for (int g = 0; g < 4; ++g) {
      int addr = (w * 16 + q * 4 + g) * 72 + col;
      u16 h2 = H2s[addr];
      H2s[addr] = h2 ? f2bf(t3acc[t][g]) : (u16)0;
    }
  }
  LDS_FENCE();
  // T2 = T3 @ W2 (natural), masked by H1>0 -> H1s
  f32x4 t2acc[4] = {};
  #pragma unroll
  for (int ks = 0; ks < 2; ++ks) {
    short8 a = *(const short8*)&H2s[arow * 72 + ks * 32 + q * 8];
    #pragma unroll
    for (int t = 0; t < 4; ++t) {
      short8 b = *(const short8*)&PW2n[((t * 2 + ks) * 64 + lane) * 8];
      t2acc[t] = MFMA(a, b, t2acc[t]);
    }
  }
  #pragma unroll
  for (int t = 0; t < 4; ++t) {
    int col = t * 16 + r;
    #pragma unroll
    for (int g = 0; g < 4; ++g) {
      int addr = (w * 16 + q * 4 + g) * 72 + col;
      u16 h1 = H1s[addr];
      H1s[addr] = h1 ? f2bf(t2acc[t][g]) : (u16)0;
    }
  }
  LDS_FENCE();
  // T2 A-fragments -> packed global (coalesced), reused for GV
  short8 v0 = *(const short8*)&H1s[arow * 72 + 0 + q * 8];
  short8 v1 = *(const short8*)&H1s[arow * 72 + 32 + q * 8];
  *(short8*)&T2P[(size_t)((strip * 2 + 0) * 64 + lane) * 8] = v0;
  *(short8*)&T2P[(size_t)((strip * 2 + 1) * 64 + lane) * 8] = v1;
  // GV = T2 @ W1^T, row norms only
  float ssq2[4] = {0.f, 0.f, 0.f, 0.f};
  #pragma unroll
  for (int nc = 0; nc < 4; ++nc) {
    f32x4 acc[8] = {};
    #pragma unroll
    for (int t = 0; t < 8; ++t) {
      short8 b0 = *(const short8*)&PW1n[(((nc * 8 + t) * 2 + 0) * 64 + lane) * 8];
      short8 b1 = *(const short8*)&PW1n[(((nc * 8 + t) * 2 + 1) * 64 + lane) * 8];
      acc[t] = MFMA(v0, b0, acc[t]);
      acc[t] = MFMA(v1, b1, acc[t]);
    }
    #pragma unroll
    for (int t = 0; t < 8; ++t)
      #pragma unroll
      for (int g = 0; g < 4; ++g) ssq2[g] += acc[t][g] * acc[t][g];
  }
  float totw = 0.f;
  #pragma unroll
  for (int g = 0; g < 4; ++g) {
    float s = ssq2[g];
    s += __shfl_xor(s, 1); s += __shfl_xor(s, 2); s += __shfl_xor(s, 4); s += __shfl_xor(s, 8);
    if (r == 0) {
      int rowg = m0 + w * 16 + q * 4 + g;
      float nm = s + ALPHA_C * lyap_row[g];
      NUM[rowg] = nm > 0.f ? nm : 0.f;
    }
    s += __shfl_xor(s, 16); s += __shfl_xor(s, 32);
    totw += s;
  }
  if (lane == 0) dred[w] = totw;
  __syncthreads();
  if (tid == 0) atomicAdd(&DP[blockIdx.x & 255], dred[0] + dred[1] + dred[2] + dred[3]);
}

// ---------------------------------------------------------------------------
// K2: recompute GV from packed T2; out = F - (num/denom)*GV  (all coalesced)
__global__ __launch_bounds__(256) void k_out(
    const u16* __restrict__ T2P, const u16* __restrict__ PW1n,
    const u16* __restrict__ FP, const float* __restrict__ NUM, const float* __restrict__ DP,
    float* __restrict__ out) {
  __shared__ float red[256];
  const int tid = threadIdx.x;
  const int lane = tid & 63, w = tid >> 6, q = lane >> 4, r = lane & 15;
  const int m0 = blockIdx.x * 64;
  const int strip = blockIdx.x * 4 + w;
  red[tid] = DP[tid];
  __syncthreads();
  for (int s = 128; s >= 1; s >>= 1) {
    if (tid < s) red[tid] += red[tid + s];
    __syncthreads();
  }
  const float inv_denom = 1.f / red[0];
  float sc[4];
  #pragma unroll
  for (int g = 0; g < 4; ++g) sc[g] = NUM[m0 + w * 16 + q * 4 + g] * inv_denom;
  short8 a0 = *(const short8*)&T2P[(size_t)((strip * 2 + 0) * 64 + lane) * 8];
  short8 a1 = *(const short8*)&T2P[(size_t)((strip * 2 + 1) * 64 + lane) * 8];
  #pragma unroll
  for (int nc = 0; nc < 4; ++nc) {
    f32x4 acc[8] = {};
    #pragma unroll
    for (int t = 0; t < 8; ++t) {
      short8 b0 = *(const short8*)&PW1n[(((nc * 8 + t) * 2 + 0) * 64 + lane) * 8];
      short8 b1 = *(const short8*)&PW1n[(((nc * 8 + t) * 2 + 1) * 64 + lane) * 8];
      acc[t] = MFMA(a0, b0, acc[t]);
      acc[t] = MFMA(a1, b1, acc[t]);
    }
    #pragma unroll
    for (int t = 0; t < 8; ++t) {
      short4v f4 = *(const short4v*)&FP[(size_t)(((strip * 4 + nc) * 8 + t) * 64 + lane) * 4];
      #pragma unroll
      for (int g = 0; g < 4; ++g) {
        out[(size_t)(m0 + w * 16 + q * 4 + g) * 512 + nc * 128 + t * 16 + r] =
            bf2f((u16)f4[g]) - sc[g] * acc[t][g];
      }
    }
  }
}

// ---------------------------------------------------------------------------
extern "C" void kernel_launch(void* const* d_in, const int* in_sizes, int n_in,
                              void* d_out, int out_size, void* d_ws, size_t ws_size,
                              hipStream_t stream) {
  const float* x  = (const float*)d_in[0];
  const float* W1 = (const float*)d_in[1];
  const float* b1 = (const float*)d_in[2];
  const float* W2 = (const float*)d_in[3];
  const float* b2 = (const float*)d_in[4];
  const float* W3 = (const float*)d_in[5];
  const float* b3 = (const float*)d_in[6];
  const float* V1 = (const float*)d_in[7];
  const float* c1 = (const float*)d_in[8];
  const float* V2 = (const float*)d_in[9];
  const float* c2 = (const float*)d_in[10];
  const float* V3 = (const float*)d_in[11];
  const float* c3 = (const float*)d_in[12];
  float* out = (float*)d_out;

  u16* FP = (u16*)d_ws;                        // 16777216 u16 = 32 MB
  float* NUM = (float*)(FP + 16777216);        // 32768 f
  float* DP  = NUM + 32768;                    // 256 f
  u16* T2P  = (u16*)(DP + 256);                // 2097152 u16
  u16* PW1T = T2P + 2097152;
  u16* PW1n = PW1T + 32768;
  u16* PV1T = PW1n + 32768;
  u16* PV1n = PV1T + 32768;
  u16* PW3T = PV1n + 32768;
  u16* PW3n = PW3T + 32768;
  u16* PW2T = PW3n + 32768;
  u16* PW2n = PW2T + 4096;
  u16* PV2T = PW2n + 4096;
  u16* PV2n = PV2T + 4096;

  hipMemsetAsync(DP, 0, 256 * sizeof(float), stream);

  k_conv<<<128, 256, 0, stream>>>(W1, W2, W3, V1, V2,
                                  PW1T, PW1n, PV1T, PV1n, PW3T, PW3n,
                                  PW2T, PW2n, PV2T, PV2n);
  k_fused<<<512, 256, 0, stream>>>(x, PW1T, b1, PW2T, b2, PW3T, b3, PV1T, c1,
                                   PV2T, PV2n, c2, V3, c3, PV1n, PW3n, PW2n, PW1n,
                                   FP, T2P, NUM, DP);
  k_out<<<512, 256, 0, stream>>>(T2P, PW1n, FP, NUM, DP, out);
}

// Round 3
// 178.262 us; speedup vs baseline: 1.5718x; 1.3647x over previous
//
#include <hip/hip_runtime.h>

#define ALPHA_C 0.9f
#define EPS_C 1e-3f

typedef unsigned short u16;
typedef __attribute__((ext_vector_type(8))) short short8;
typedef __attribute__((ext_vector_type(4))) short short4v;
typedef __attribute__((ext_vector_type(4))) float f32x4;
#define MFMA(a, b, c) __builtin_amdgcn_mfma_f32_16x16x32_bf16(a, b, c, 0, 0, 0)
// compiler-only ordering fence; wave-private LDS hazards are in-order in HW
#define LDS_FENCE() asm volatile("" ::: "memory")

__device__ __forceinline__ u16 f2bf(float f) {
  union { float f; unsigned u; } v; v.f = f;
  unsigned u = v.u;
  u += 0x7FFFu + ((u >> 16) & 1u);
  return (u16)(u >> 16);
}
__device__ __forceinline__ float bf2f(u16 h) {
  union { unsigned u; float f; } v; v.u = ((unsigned)h) << 16;
  return v.f;
}

// ---------------------------------------------------------------------------
// K0: weight conversion fp32 -> bf16, packed in MFMA B-fragment order:
// P[((tile*KS + ks)*64 + lane)*8 + e] == 1KB contiguous per (tile,ks) wave load
__global__ __launch_bounds__(256) void k_conv(
    const float* __restrict__ W1, const float* __restrict__ W2, const float* __restrict__ W3,
    const float* __restrict__ V1, const float* __restrict__ V2,
    u16* __restrict__ PW1T, u16* __restrict__ PW1n, u16* __restrict__ PV1T, u16* __restrict__ PV1n,
    u16* __restrict__ PW3T, u16* __restrict__ PW3n, u16* __restrict__ PW2T, u16* __restrict__ PW2n,
    u16* __restrict__ PV2T, u16* __restrict__ PV2n) {
  int i = blockIdx.x * 256 + threadIdx.x;   // 0..32767
  {
    int k = i >> 6, j = i & 63;             // W1[k][j], V1[k][j]  (512x64)
    u16 b = f2bf(W1[i]);
    PW1T[((((j >> 4) * 16 + (k >> 5)) * 4 + ((k & 31) >> 3)) * 16 + (j & 15)) * 8 + (k & 7)] = b;
    PW1n[((((k >> 4) * 2 + (j >> 5)) * 4 + ((j & 31) >> 3)) * 16 + (k & 15)) * 8 + (j & 7)] = b;
    u16 c = f2bf(V1[i]);
    PV1T[((((j >> 4) * 16 + (k >> 5)) * 4 + ((k & 31) >> 3)) * 16 + (j & 15)) * 8 + (k & 7)] = c;
    PV1n[((((k >> 4) * 2 + (j >> 5)) * 4 + ((j & 31) >> 3)) * 16 + (k & 15)) * 8 + (j & 7)] = c;
  }
  {
    int k = i >> 9, n = i & 511;            // W3[k][n] (64x512)
    u16 b = f2bf(W3[i]);
    PW3T[((((n >> 4) * 2 + (k >> 5)) * 4 + ((k & 31) >> 3)) * 16 + (n & 15)) * 8 + (k & 7)] = b;
    PW3n[((((k >> 4) * 16 + (n >> 5)) * 4 + ((n & 31) >> 3)) * 16 + (k & 15)) * 8 + (n & 7)] = b;
  }
  if (i < 4096) {
    int k = i >> 6, j = i & 63;             // W2[k][j], V2[k][j] (64x64)
    u16 b = f2bf(W2[i]);
    PW2T[((((j >> 4) * 2 + (k >> 5)) * 4 + ((k & 31) >> 3)) * 16 + (j & 15)) * 8 + (k & 7)] = b;
    PW2n[((((k >> 4) * 2 + (j >> 5)) * 4 + ((j & 31) >> 3)) * 16 + (k & 15)) * 8 + (j & 7)] = b;
    u16 c = f2bf(V2[i]);
    PV2T[((((j >> 4) * 2 + (k >> 5)) * 4 + ((k & 31) >> 3)) * 16 + (j & 15)) * 8 + (k & 7)] = c;
    PV2n[((((k >> 4) * 2 + (j >> 5)) * 4 + ((j & 31) >> 3)) * 16 + (k & 15)) * 8 + (j & 7)] = c;
  }
}

// ---------------------------------------------------------------------------
__global__ __launch_bounds__(256, 2) void k_fused(
    const float* __restrict__ x,
    const u16* __restrict__ PW1T, const float* __restrict__ b1,
    const u16* __restrict__ PW2T, const float* __restrict__ b2,
    const u16* __restrict__ PW3T, const float* __restrict__ b3,
    const u16* __restrict__ PV1T, const float* __restrict__ c1,
    const u16* __restrict__ PV2T, const u16* __restrict__ PV2n, const float* __restrict__ c2,
    const float* __restrict__ V3, const float* __restrict__ c3,
    const u16* __restrict__ PV1n, const u16* __restrict__ PW3n,
    const u16* __restrict__ PW2n, const u16* __restrict__ PW1n,
    u16* __restrict__ FP, u16* __restrict__ T2P,
    float* __restrict__ NUM, float* __restrict__ DP) {
  __shared__ u16 H1s[64 * 72];
  __shared__ u16 H2s[64 * 72];
  __shared__ u16 S2s[64 * 72];
  __shared__ u16 As[64 * 136];
  __shared__ float dred[4];
  const int tid = threadIdx.x;
  const int lane = tid & 63, w = tid >> 6, q = lane >> 4, r = lane & 15;
  const int m0 = blockIdx.x * 64;
  const int arow = w * 16 + r;
  const int strip = blockIdx.x * 4 + w;
  const int h = lane >> 5, c4 = lane & 31;   // staging coords
  const float* xbase = x + (size_t)(m0 + w * 16) * 512;

  // ---- phase A1: H1 = relu(x @ W1 + b1); x staged per-128-col chunk, dbuf'd
  f32x4 acc1[4] = {};
  float4 xr0[8], xr1[8];

#define LOAD_X(regs, kc)                                                        \
  _Pragma("unroll") for (int it = 0; it < 8; ++it)                              \
    regs[it] = *(const float4*)&xbase[(it * 2 + h) * 512 + (kc) * 128 + c4 * 4];

#define STAGE_X(regs)                                                           \
  _Pragma("unroll") for (int it = 0; it < 8; ++it) {                            \
    float4 v = regs[it];                                                        \
    short4v s4;                                                                 \
    s4[0] = (short)f2bf(v.x); s4[1] = (short)f2bf(v.y);                         \
    s4[2] = (short)f2bf(v.z); s4[3] = (short)f2bf(v.w);                         \
    *(short4v*)&As[(w * 16 + it * 2 + h) * 136 + c4 * 4] = s4;                  \
  }

#define MFMA_X(kc)                                                              \
  _Pragma("unroll") for (int ks = 0; ks < 4; ++ks) {                            \
    short8 a = *(const short8*)&As[arow * 136 + ks * 32 + q * 8];               \
    _Pragma("unroll") for (int t = 0; t < 4; ++t) {                             \
      short8 b = *(const short8*)&PW1T[((t * 16 + (kc) * 4 + ks) * 64 + lane) * 8]; \
      acc1[t] = MFMA(a, b, acc1[t]);                                            \
    }                                                                           \
  }

  LOAD_X(xr0, 0)
  STAGE_X(xr0) LDS_FENCE(); LOAD_X(xr1, 1) MFMA_X(0) LDS_FENCE();
  STAGE_X(xr1) LDS_FENCE(); LOAD_X(xr0, 2) MFMA_X(1) LDS_FENCE();
  STAGE_X(xr0) LDS_FENCE(); LOAD_X(xr1, 3) MFMA_X(2) LDS_FENCE();
  STAGE_X(xr1) LDS_FENCE(); MFMA_X(3)

  #pragma unroll
  for (int t = 0; t < 4; ++t) {
    int col = t * 16 + r; float bv = b1[col];
    #pragma unroll
    for (int g = 0; g < 4; ++g) {
      float hh = acc1[t][g] + bv; hh = hh > 0.f ? hh : 0.f;
      H1s[(w * 16 + q * 4 + g) * 72 + col] = f2bf(hh);
    }
  }
  LDS_FENCE();

  // ---- phase A2: H2 = relu(H1 @ W2 + b2)
  f32x4 acc2[4] = {};
  #pragma unroll
  for (int ks = 0; ks < 2; ++ks) {
    short8 a = *(const short8*)&H1s[arow * 72 + ks * 32 + q * 8];
    #pragma unroll
    for (int t = 0; t < 4; ++t) {
      short8 b = *(const short8*)&PW2T[((t * 2 + ks) * 64 + lane) * 8];
      acc2[t] = MFMA(a, b, acc2[t]);
    }
  }
  #pragma unroll
  for (int t = 0; t < 4; ++t) {
    int col = t * 16 + r; float bv = b2[col];
    #pragma unroll
    for (int g = 0; g < 4; ++g) {
      float hh = acc2[t][g] + bv; hh = hh > 0.f ? hh : 0.f;
      H2s[(w * 16 + q * 4 + g) * 72 + col] = f2bf(hh);
    }
  }
  LDS_FENCE();

  // ---- phase B: F = H2 @ W3 + b3 (packed store), G1 accum = F @ V1  [ROLLED]
  f32x4 g1acc[4] = {};
  float ssq[4] = {0.f, 0.f, 0.f, 0.f};
  #pragma unroll 1
  for (int nc = 0; nc < 4; ++nc) {
    f32x4 facc[8] = {};
    #pragma unroll
    for (int ks = 0; ks < 2; ++ks) {
      short8 a = *(const short8*)&H2s[arow * 72 + ks * 32 + q * 8];
      #pragma unroll
      for (int t = 0; t < 8; ++t) {
        short8 b = *(const short8*)&PW3T[(((nc * 8 + t) * 2 + ks) * 64 + lane) * 8];
        facc[t] = MFMA(a, b, facc[t]);
      }
    }
    #pragma unroll
    for (int t = 0; t < 8; ++t) {
      float bv = b3[nc * 128 + t * 16 + r];
      short4v s4;
      #pragma unroll
      for (int g = 0; g < 4; ++g) {
        float v = facc[t][g] + bv;
        ssq[g] += v * v;
        u16 bb = f2bf(v);
        As[(w * 16 + q * 4 + g) * 136 + t * 16 + r] = bb;
        s4[g] = (short)bb;
      }
      *(short4v*)&FP[(size_t)(((strip * 4 + nc) * 8 + t) * 64 + lane) * 4] = s4;
    }
    LDS_FENCE();
    #pragma unroll
    for (int ks = 0; ks < 4; ++ks) {
      short8 a = *(const short8*)&As[arow * 136 + ks * 32 + q * 8];
      #pragma unroll
      for (int t = 0; t < 4; ++t) {
        short8 b = *(const short8*)&PV1T[((t * 16 + nc * 4 + ks) * 64 + lane) * 8];
        g1acc[t] = MFMA(a, b, g1acc[t]);
      }
    }
    LDS_FENCE();
  }

  // G1 = relu(g1acc + c1) -> S2s
  f32x4 g1v[4];
  #pragma unroll
  for (int t = 0; t < 4; ++t) {
    int col = t * 16 + r; float cv = c1[col];
    #pragma unroll
    for (int g = 0; g < 4; ++g) {
      float v = g1acc[t][g] + cv; v = v > 0.f ? v : 0.f;
      g1v[t][g] = v;
      S2s[(w * 16 + q * 4 + g) * 72 + col] = f2bf(v);
    }
  }
  LDS_FENCE();
  // g2 = G1 @ V2T
  f32x4 g2acc[4] = {};
  #pragma unroll
  for (int ks = 0; ks < 2; ++ks) {
    short8 a = *(const short8*)&S2s[arow * 72 + ks * 32 + q * 8];
    #pragma unroll
    for (int t = 0; t < 4; ++t) {
      short8 b = *(const short8*)&PV2T[((t * 2 + ks) * 64 + lane) * 8];
      g2acc[t] = MFMA(a, b, g2acc[t]);
    }
  }
  // s3 = (g2pre>0)*V3 -> S2s; lyap partial
  float tot[4] = {0.f, 0.f, 0.f, 0.f};
  #pragma unroll
  for (int t = 0; t < 4; ++t) {
    int col = t * 16 + r;
    float c2v = c2[col], v3v = V3[col];
    #pragma unroll
    for (int g = 0; g < 4; ++g) {
      float pre = g2acc[t][g] + c2v;
      float g2 = pre > 0.f ? pre : 0.f;
      S2s[(w * 16 + q * 4 + g) * 72 + col] = pre > 0.f ? f2bf(v3v) : (u16)0;
      tot[g] += g2 * v3v;
    }
  }
  LDS_FENCE();
  // s2 = s3 @ V2 (natural), masked by G1>0 -> S2s
  f32x4 s2acc[4] = {};
  #pragma unroll
  for (int ks = 0; ks < 2; ++ks) {
    short8 a = *(const short8*)&S2s[arow * 72 + ks * 32 + q * 8];
    #pragma unroll
    for (int t = 0; t < 4; ++t) {
      short8 b = *(const short8*)&PV2n[((t * 2 + ks) * 64 + lane) * 8];
      s2acc[t] = MFMA(a, b, s2acc[t]);
    }
  }
  #pragma unroll
  for (int t = 0; t < 4; ++t) {
    int col = t * 16 + r;
    #pragma unroll
    for (int g = 0; g < 4; ++g) {
      float sv = g1v[t][g] > 0.f ? s2acc[t][g] : 0.f;
      S2s[(w * 16 + q * 4 + g) * 72 + col] = f2bf(sv);
    }
  }
  LDS_FENCE();
  float c3v = c3[0];
  float lyap_row[4];
  #pragma unroll
  for (int g = 0; g < 4; ++g) {
    float s = tot[g] + EPS_C * ssq[g];
    s += __shfl_xor(s, 1); s += __shfl_xor(s, 2); s += __shfl_xor(s, 4); s += __shfl_xor(s, 8);
    lyap_row[g] = s + c3v;
  }

  // all FP stores must land before same-address re-reads in phase C
  asm volatile("s_waitcnt vmcnt(0)" ::: "memory");

  // ---- phase C: U = s2 @ V1^T + 2eps*F; T3 accum = (U) @ W3^T  [ROLLED]
  f32x4 t3acc[4] = {};
  #pragma unroll 1
  for (int nc = 0; nc < 4; ++nc) {
    f32x4 uacc[8] = {};
    #pragma unroll
    for (int ks = 0; ks < 2; ++ks) {
      short8 a = *(const short8*)&S2s[arow * 72 + ks * 32 + q * 8];
      #pragma unroll
      for (int t = 0; t < 8; ++t) {
        short8 b = *(const short8*)&PV1n[(((nc * 8 + t) * 2 + ks) * 64 + lane) * 8];
        uacc[t] = MFMA(a, b, uacc[t]);
      }
    }
    #pragma unroll
    for (int t = 0; t < 8; ++t) {
      short4v f4 = *(const short4v*)&FP[(size_t)(((strip * 4 + nc) * 8 + t) * 64 + lane) * 4];
      #pragma unroll
      for (int g = 0; g < 4; ++g) {
        As[(w * 16 + q * 4 + g) * 136 + t * 16 + r] =
            f2bf(uacc[t][g] + 2.f * EPS_C * bf2f((u16)f4[g]));
      }
    }
    LDS_FENCE();
    #pragma unroll
    for (int ks = 0; ks < 4; ++ks) {
      short8 a = *(const short8*)&As[arow * 136 + ks * 32 + q * 8];
      #pragma unroll
      for (int t = 0; t < 4; ++t) {
        short8 b = *(const short8*)&PW3n[((t * 16 + nc * 4 + ks) * 64 + lane) * 8];
        t3acc[t] = MFMA(a, b, t3acc[t]);
      }
    }
    LDS_FENCE();
  }
  // T3 masked by H2>0 -> H2s
  #pragma unroll
  for (int t = 0; t < 4; ++t) {
    int col = t * 16 + r;
    #pragma unroll
    for (int g = 0; g < 4; ++g) {
      int addr = (w * 16 + q * 4 + g) * 72 + col;
      u16 h2 = H2s[addr];
      H2s[addr] = h2 ? f2bf(t3acc[t][g]) : (u16)0;
    }
  }
  LDS_FENCE();
  // T2 = T3 @ W2 (natural), masked by H1>0 -> H1s
  f32x4 t2acc[4] = {};
  #pragma unroll
  for (int ks = 0; ks < 2; ++ks) {
    short8 a = *(const short8*)&H2s[arow * 72 + ks * 32 + q * 8];
    #pragma unroll
    for (int t = 0; t < 4; ++t) {
      short8 b = *(const short8*)&PW2n[((t * 2 + ks) * 64 + lane) * 8];
      t2acc[t] = MFMA(a, b, t2acc[t]);
    }
  }
  #pragma unroll
  for (int t = 0; t < 4; ++t) {
    int col = t * 16 + r;
    #pragma unroll
    for (int g = 0; g < 4; ++g) {
      int addr = (w * 16 + q * 4 + g) * 72 + col;
      u16 h1 = H1s[addr];
      H1s[addr] = h1 ? f2bf(t2acc[t][g]) : (u16)0;
    }
  }
  LDS_FENCE();
  // T2 A-fragments -> packed global (coalesced), reused for GV
  short8 v0 = *(const short8*)&H1s[arow * 72 + 0 + q * 8];
  short8 v1 = *(const short8*)&H1s[arow * 72 + 32 + q * 8];
  *(short8*)&T2P[(size_t)((strip * 2 + 0) * 64 + lane) * 8] = v0;
  *(short8*)&T2P[(size_t)((strip * 2 + 1) * 64 + lane) * 8] = v1;
  // GV = T2 @ W1^T, row norms only  [ROLLED]
  float ssq2[4] = {0.f, 0.f, 0.f, 0.f};
  #pragma unroll 1
  for (int nc = 0; nc < 4; ++nc) {
    f32x4 acc[8] = {};
    #pragma unroll
    for (int t = 0; t < 8; ++t) {
      short8 b0 = *(const short8*)&PW1n[(((nc * 8 + t) * 2 + 0) * 64 + lane) * 8];
      short8 b1 = *(const short8*)&PW1n[(((nc * 8 + t) * 2 + 1) * 64 + lane) * 8];
      acc[t] = MFMA(v0, b0, acc[t]);
      acc[t] = MFMA(v1, b1, acc[t]);
    }
    #pragma unroll
    for (int t = 0; t < 8; ++t)
      #pragma unroll
      for (int g = 0; g < 4; ++g) ssq2[g] += acc[t][g] * acc[t][g];
  }
  float totw = 0.f;
  #pragma unroll
  for (int g = 0; g < 4; ++g) {
    float s = ssq2[g];
    s += __shfl_xor(s, 1); s += __shfl_xor(s, 2); s += __shfl_xor(s, 4); s += __shfl_xor(s, 8);
    if (r == 0) {
      int rowg = m0 + w * 16 + q * 4 + g;
      float nm = s + ALPHA_C * lyap_row[g];
      NUM[rowg] = nm > 0.f ? nm : 0.f;
    }
    s += __shfl_xor(s, 16); s += __shfl_xor(s, 32);
    totw += s;
  }
  if (lane == 0) dred[w] = totw;
  __syncthreads();
  if (tid == 0) atomicAdd(&DP[blockIdx.x & 255], dred[0] + dred[1] + dred[2] + dred[3]);
}

// ---------------------------------------------------------------------------
// K2: recompute GV from packed T2; out = F - (num/denom)*GV  (all coalesced)
__global__ __launch_bounds__(256) void k_out(
    const u16* __restrict__ T2P, const u16* __restrict__ PW1n,
    const u16* __restrict__ FP, const float* __restrict__ NUM, const float* __restrict__ DP,
    float* __restrict__ out) {
  __shared__ float red[256];
  const int tid = threadIdx.x;
  const int lane = tid & 63, w = tid >> 6, q = lane >> 4, r = lane & 15;
  const int m0 = blockIdx.x * 64;
  const int strip = blockIdx.x * 4 + w;
  red[tid] = DP[tid];
  __syncthreads();
  for (int s = 128; s >= 1; s >>= 1) {
    if (tid < s) red[tid] += red[tid + s];
    __syncthreads();
  }
  const float inv_denom = 1.f / red[0];
  float sc[4];
  #pragma unroll
  for (int g = 0; g < 4; ++g) sc[g] = NUM[m0 + w * 16 + q * 4 + g] * inv_denom;
  short8 a0 = *(const short8*)&T2P[(size_t)((strip * 2 + 0) * 64 + lane) * 8];
  short8 a1 = *(const short8*)&T2P[(size_t)((strip * 2 + 1) * 64 + lane) * 8];
  #pragma unroll 1
  for (int nc = 0; nc < 4; ++nc) {
    f32x4 acc[8] = {};
    #pragma unroll
    for (int t = 0; t < 8; ++t) {
      short8 b0 = *(const short8*)&PW1n[(((nc * 8 + t) * 2 + 0) * 64 + lane) * 8];
      short8 b1 = *(const short8*)&PW1n[(((nc * 8 + t) * 2 + 1) * 64 + lane) * 8];
      acc[t] = MFMA(a0, b0, acc[t]);
      acc[t] = MFMA(a1, b1, acc[t]);
    }
    #pragma unroll
    for (int t = 0; t < 8; ++t) {
      short4v f4 = *(const short4v*)&FP[(size_t)(((strip * 4 + nc) * 8 + t) * 64 + lane) * 4];
      #pragma unroll
      for (int g = 0; g < 4; ++g) {
        out[(size_t)(m0 + w * 16 + q * 4 + g) * 512 + nc * 128 + t * 16 + r] =
            bf2f((u16)f4[g]) - sc[g] * acc[t][g];
      }
    }
  }
}

// ---------------------------------------------------------------------------
extern "C" void kernel_launch(void* const* d_in, const int* in_sizes, int n_in,
                              void* d_out, int out_size, void* d_ws, size_t ws_size,
                              hipStream_t stream) {
  const float* x  = (const float*)d_in[0];
  const float* W1 = (const float*)d_in[1];
  const float* b1 = (const float*)d_in[2];
  const float* W2 = (const float*)d_in[3];
  const float* b2 = (const float*)d_in[4];
  const float* W3 = (const float*)d_in[5];
  const float* b3 = (const float*)d_in[6];
  const float* V1 = (const float*)d_in[7];
  const float* c1 = (const float*)d_in[8];
  const float* V2 = (const float*)d_in[9];
  const float* c2 = (const float*)d_in[10];
  const float* V3 = (const float*)d_in[11];
  const float* c3 = (const float*)d_in[12];
  float* out = (float*)d_out;

  u16* FP = (u16*)d_ws;                        // 16777216 u16 = 32 MB
  float* NUM = (float*)(FP + 16777216);        // 32768 f
  float* DP  = NUM + 32768;                    // 256 f
  u16* T2P  = (u16*)(DP + 256);                // 2097152 u16
  u16* PW1T = T2P + 2097152;
  u16* PW1n = PW1T + 32768;
  u16* PV1T = PW1n + 32768;
  u16* PV1n = PV1T + 32768;
  u16* PW3T = PV1n + 32768;
  u16* PW3n = PW3T + 32768;
  u16* PW2T = PW3n + 32768;
  u16* PW2n = PW2T + 4096;
  u16* PV2T = PW2n + 4096;
  u16* PV2n = PV2T + 4096;

  hipMemsetAsync(DP, 0, 256 * sizeof(float), stream);

  k_conv<<<128, 256, 0, stream>>>(W1, W2, W3, V1, V2,
                                  PW1T, PW1n, PV1T, PV1n, PW3T, PW3n,
                                  PW2T, PW2n, PV2T, PV2n);
  k_fused<<<512, 256, 0, stream>>>(x, PW1T, b1, PW2T, b2, PW3T, b3, PV1T, c1,
                                   PV2T, PV2n, c2, V3, c3, PV1n, PW3n, PW2n, PW1n,
                                   FP, T2P, NUM, DP);
  k_out<<<512, 256, 0, stream>>>(T2P, PW1n, FP, NUM, DP, out);
}

// Round 4
// 178.125 us; speedup vs baseline: 1.5730x; 1.0008x over previous
//
#include <hip/hip_runtime.h>

#define ALPHA_C 0.9f
#define EPS_C 1e-3f

typedef unsigned short u16;
typedef __attribute__((ext_vector_type(8))) short short8;
typedef __attribute__((ext_vector_type(4))) short short4v;
typedef __attribute__((ext_vector_type(4))) float f32x4;
#define MFMA(a, b, c) __builtin_amdgcn_mfma_f32_16x16x32_bf16(a, b, c, 0, 0, 0)
// compiler-only ordering fence; wave-private LDS hazards are in-order in HW
#define LDS_FENCE() asm volatile("" ::: "memory")

__device__ __forceinline__ u16 f2bf(float f) {
  union { float f; unsigned u; } v; v.f = f;
  unsigned u = v.u;
  u += 0x7FFFu + ((u >> 16) & 1u);
  return (u16)(u >> 16);
}
__device__ __forceinline__ float bf2f(u16 h) {
  union { unsigned u; float f; } v; v.u = ((unsigned)h) << 16;
  return v.f;
}

// ---------------------------------------------------------------------------
// K0: weight conversion fp32 -> bf16, packed in MFMA B-fragment order.
__global__ __launch_bounds__(256) void k_conv(
    const float* __restrict__ W1, const float* __restrict__ W2, const float* __restrict__ W3,
    const float* __restrict__ V1, const float* __restrict__ V2,
    u16* __restrict__ PW1T, u16* __restrict__ PW1n, u16* __restrict__ PV1T, u16* __restrict__ PV1n,
    u16* __restrict__ PW3T, u16* __restrict__ PW3n, u16* __restrict__ PW2T, u16* __restrict__ PW2n,
    u16* __restrict__ PV2T, u16* __restrict__ PV2n, float* __restrict__ DP) {
  int i = blockIdx.x * 256 + threadIdx.x;   // 0..32767
  if (i < 256) DP[i] = 0.f;
  {
    int k = i >> 6, j = i & 63;             // W1[k][j], V1[k][j]  (512x64)
    u16 b = f2bf(W1[i]);
    PW1T[((((j >> 4) * 16 + (k >> 5)) * 4 + ((k & 31) >> 3)) * 16 + (j & 15)) * 8 + (k & 7)] = b;
    PW1n[((((k >> 4) * 2 + (j >> 5)) * 4 + ((j & 31) >> 3)) * 16 + (k & 15)) * 8 + (j & 7)] = b;
    u16 c = f2bf(V1[i]);
    PV1T[((((j >> 4) * 16 + (k >> 5)) * 4 + ((k & 31) >> 3)) * 16 + (j & 15)) * 8 + (k & 7)] = c;
    PV1n[((((k >> 4) * 2 + (j >> 5)) * 4 + ((j & 31) >> 3)) * 16 + (k & 15)) * 8 + (j & 7)] = c;
  }
  {
    int k = i >> 9, n = i & 511;            // W3[k][n] (64x512)
    u16 b = f2bf(W3[i]);
    PW3T[((((n >> 4) * 2 + (k >> 5)) * 4 + ((k & 31) >> 3)) * 16 + (n & 15)) * 8 + (k & 7)] = b;
    PW3n[((((k >> 4) * 16 + (n >> 5)) * 4 + ((n & 31) >> 3)) * 16 + (k & 15)) * 8 + (n & 7)] = b;
  }
  if (i < 4096) {
    int k = i >> 6, j = i & 63;             // W2[k][j], V2[k][j] (64x64)
    u16 b = f2bf(W2[i]);
    PW2T[((((j >> 4) * 2 + (k >> 5)) * 4 + ((k & 31) >> 3)) * 16 + (j & 15)) * 8 + (k & 7)] = b;
    PW2n[((((k >> 4) * 2 + (j >> 5)) * 4 + ((j & 31) >> 3)) * 16 + (k & 15)) * 8 + (j & 7)] = b;
    u16 c = f2bf(V2[i]);
    PV2T[((((j >> 4) * 2 + (k >> 5)) * 4 + ((k & 31) >> 3)) * 16 + (j & 15)) * 8 + (k & 7)] = c;
    PV2n[((((k >> 4) * 2 + (j >> 5)) * 4 + ((j & 31) >> 3)) * 16 + (k & 15)) * 8 + (j & 7)] = c;
  }
}

// helper: load 8 b-fragments (frag index expression in j)
#define LDG8(dst, P, FRAG)                                                      \
  _Pragma("unroll") for (int j = 0; j < 8; ++j)                                 \
    dst[j] = *(const short8*)&P[((size_t)(FRAG) * 64 + lane) * 8];

// ---------------------------------------------------------------------------
__global__ __launch_bounds__(256, 2) void k_fused(
    const float* __restrict__ x,
    const u16* __restrict__ PW1T, const float* __restrict__ b1,
    const u16* __restrict__ PW2T, const float* __restrict__ b2,
    const u16* __restrict__ PW3T, const float* __restrict__ b3,
    const u16* __restrict__ PV1T, const float* __restrict__ c1,
    const u16* __restrict__ PV2T, const u16* __restrict__ PV2n, const float* __restrict__ c2,
    const float* __restrict__ V3, const float* __restrict__ c3,
    const u16* __restrict__ PV1n, const u16* __restrict__ PW3n,
    const u16* __restrict__ PW2n, const u16* __restrict__ PW1n,
    u16* __restrict__ FP, u16* __restrict__ T2P,
    float* __restrict__ NUM, float* __restrict__ DP) {
  __shared__ u16 H1s[64 * 72];
  __shared__ u16 H2s[64 * 72];
  __shared__ u16 S2s[64 * 72];
  __shared__ u16 As[64 * 136];
  __shared__ float dred[4];
  const int tid = threadIdx.x;
  const int lane = tid & 63, w = tid >> 6, q = lane >> 4, r = lane & 15;
  const int m0 = blockIdx.x * 64;
  const int arow = w * 16 + r;
  const int strip = blockIdx.x * 4 + w;
  const int h = lane >> 5, c4 = lane & 31;
  const float* xbase = x + (size_t)(m0 + w * 16) * 512;

  short8 bA[8], bB[8];     // rotating weight-fragment buffers (prefetch)

  // ================= phase A1: H1 = relu(x @ W1 + b1) =================
  f32x4 acc1[4] = {};
  float4 xr[8];
  #pragma unroll
  for (int it = 0; it < 8; ++it)
    xr[it] = *(const float4*)&xbase[(it * 2 + h) * 512 + c4 * 4];
  LDG8(bA, PW1T, (j & 3) * 16 + 0 * 4 + (j >> 2));   // kc0 G0 (ks0,1)

#define A1_STEP(kc, LAST)                                                       \
  {                                                                             \
    _Pragma("unroll") for (int it = 0; it < 8; ++it) {                          \
      float4 v = xr[it]; short4v s4;                                            \
      s4[0] = (short)f2bf(v.x); s4[1] = (short)f2bf(v.y);                       \
      s4[2] = (short)f2bf(v.z); s4[3] = (short)f2bf(v.w);                       \
      *(short4v*)&As[(w * 16 + it * 2 + h) * 136 + c4 * 4] = s4;                \
    }                                                                           \
    LDS_FENCE();                                                                \
    if (!LAST) {                                                                \
      _Pragma("unroll") for (int it = 0; it < 8; ++it)                          \
        xr[it] = *(const float4*)&xbase[(it * 2 + h) * 512 + (kc + 1) * 128 + c4 * 4]; \
    }                                                                           \
    LDG8(bB, PW1T, (j & 3) * 16 + (kc) * 4 + 2 + (j >> 2));  /* G1 ks2,3 */     \
    short8 a0 = *(const short8*)&As[arow * 136 + 0 * 32 + q * 8];               \
    short8 a1 = *(const short8*)&As[arow * 136 + 1 * 32 + q * 8];               \
    _Pragma("unroll") for (int t = 0; t < 4; ++t) acc1[t] = MFMA(a0, bA[t], acc1[t]); \
    _Pragma("unroll") for (int t = 0; t < 4; ++t) acc1[t] = MFMA(a1, bA[4 + t], acc1[t]); \
    if (!LAST) { LDG8(bA, PW1T, (j & 3) * 16 + (kc + 1) * 4 + (j >> 2)); }      \
    else       { LDG8(bA, PW2T, (j & 3) * 2 + (j >> 2)); }   /* A2 frags */     \
    short8 a2 = *(const short8*)&As[arow * 136 + 2 * 32 + q * 8];               \
    short8 a3 = *(const short8*)&As[arow * 136 + 3 * 32 + q * 8];               \
    _Pragma("unroll") for (int t = 0; t < 4; ++t) acc1[t] = MFMA(a2, bB[t], acc1[t]); \
    _Pragma("unroll") for (int t = 0; t < 4; ++t) acc1[t] = MFMA(a3, bB[4 + t], acc1[t]); \
  }

  A1_STEP(0, 0) A1_STEP(1, 0) A1_STEP(2, 0) A1_STEP(3, 1)

  #pragma unroll
  for (int t = 0; t < 4; ++t) {
    int col = t * 16 + r; float bv = b1[col];
    #pragma unroll
    for (int g = 0; g < 4; ++g) {
      float hh = acc1[t][g] + bv; hh = hh > 0.f ? hh : 0.f;
      H1s[(w * 16 + q * 4 + g) * 72 + col] = f2bf(hh);
    }
  }
  LDS_FENCE();

  // ================= phase A2: H2 = relu(H1 @ W2 + b2) =================
  {
    short8 a0 = *(const short8*)&H1s[arow * 72 + 0 + q * 8];
    short8 a1 = *(const short8*)&H1s[arow * 72 + 32 + q * 8];
    f32x4 acc2[4] = {};
    #pragma unroll
    for (int t = 0; t < 4; ++t) acc2[t] = MFMA(a0, bA[t], acc2[t]);
    LDG8(bB, PW3T, ((j & 3)) * 2 + (j >> 2));        // B prologue: W3T nc0 t03
    #pragma unroll
    for (int t = 0; t < 4; ++t) acc2[t] = MFMA(a1, bA[4 + t], acc2[t]);
    #pragma unroll
    for (int t = 0; t < 4; ++t) {
      int col = t * 16 + r; float bv = b2[col];
      #pragma unroll
      for (int g = 0; g < 4; ++g) {
        float hh = acc2[t][g] + bv; hh = hh > 0.f ? hh : 0.f;
        H2s[(w * 16 + q * 4 + g) * 72 + col] = f2bf(hh);
      }
    }
  }
  LDS_FENCE();

  // ================= phase B: F = H2 @ W3 + b3; G1 accum = F @ V1 =================
  f32x4 g1acc[4] = {};
  float ssq[4] = {0.f, 0.f, 0.f, 0.f};
  short8 h2a0 = *(const short8*)&H2s[arow * 72 + 0 + q * 8];
  short8 h2a1 = *(const short8*)&H2s[arow * 72 + 32 + q * 8];
  #pragma unroll 1
  for (int nc = 0; nc < 4; ++nc) {
    // bB holds W3T[nc] t0-3 (j = ks*4+t)
    LDG8(bA, PW3T, ((nc * 8 + 4 + (j & 3)) * 2 + (j >> 2)));     // t4-7
    f32x4 facc[8] = {};
    #pragma unroll
    for (int t = 0; t < 4; ++t) facc[t] = MFMA(h2a0, bB[t], facc[t]);
    #pragma unroll
    for (int t = 0; t < 4; ++t) facc[t] = MFMA(h2a1, bB[4 + t], facc[t]);
    LDG8(bB, PV1T, ((j & 3) * 16 + nc * 4 + (j >> 2)));          // V1T ks0,1
    #pragma unroll
    for (int t = 0; t < 4; ++t) facc[4 + t] = MFMA(h2a0, bA[t], facc[4 + t]);
    #pragma unroll
    for (int t = 0; t < 4; ++t) facc[4 + t] = MFMA(h2a1, bA[4 + t], facc[4 + t]);
    LDG8(bA, PV1T, ((j & 3) * 16 + nc * 4 + 2 + (j >> 2)));      // V1T ks2,3
    #pragma unroll
    for (int t = 0; t < 8; ++t) {
      float bv = b3[nc * 128 + t * 16 + r];
      short4v s4;
      #pragma unroll
      for (int g = 0; g < 4; ++g) {
        float v = facc[t][g] + bv;
        ssq[g] += v * v;
        u16 bb = f2bf(v);
        As[(w * 16 + q * 4 + g) * 136 + t * 16 + r] = bb;
        s4[g] = (short)bb;
      }
      *(short4v*)&FP[(size_t)(((strip * 4 + nc) * 8 + t) * 64 + lane) * 4] = s4;
    }
    LDS_FENCE();
    short8 a0 = *(const short8*)&As[arow * 136 + 0 * 32 + q * 8];
    short8 a1 = *(const short8*)&As[arow * 136 + 1 * 32 + q * 8];
    #pragma unroll
    for (int t = 0; t < 4; ++t) g1acc[t] = MFMA(a0, bB[t], g1acc[t]);
    #pragma unroll
    for (int t = 0; t < 4; ++t) g1acc[t] = MFMA(a1, bB[4 + t], g1acc[t]);
    int ncn = (nc + 1) & 3;
    LDG8(bB, PW3T, ((ncn * 8 + (j & 3)) * 2 + (j >> 2)));        // next t0-3
    short8 a2 = *(const short8*)&As[arow * 136 + 2 * 32 + q * 8];
    short8 a3 = *(const short8*)&As[arow * 136 + 3 * 32 + q * 8];
    #pragma unroll
    for (int t = 0; t < 4; ++t) g1acc[t] = MFMA(a2, bA[t], g1acc[t]);
    #pragma unroll
    for (int t = 0; t < 4; ++t) g1acc[t] = MFMA(a3, bA[4 + t], g1acc[t]);
    LDS_FENCE();
  }

  // G1 = relu(g1acc + c1) -> S2s
  f32x4 g1v[4];
  #pragma unroll
  for (int t = 0; t < 4; ++t) {
    int col = t * 16 + r; float cv = c1[col];
    #pragma unroll
    for (int g = 0; g < 4; ++g) {
      float v = g1acc[t][g] + cv; v = v > 0.f ? v : 0.f;
      g1v[t][g] = v;
      S2s[(w * 16 + q * 4 + g) * 72 + col] = f2bf(v);
    }
  }
  LDG8(bA, PV2T, (j & 3) * 2 + (j >> 2));
  LDS_FENCE();
  // g2 = G1 @ V2T
  f32x4 g2acc[4] = {};
  {
    short8 a0 = *(const short8*)&S2s[arow * 72 + 0 + q * 8];
    short8 a1 = *(const short8*)&S2s[arow * 72 + 32 + q * 8];
    #pragma unroll
    for (int t = 0; t < 4; ++t) g2acc[t] = MFMA(a0, bA[t], g2acc[t]);
    #pragma unroll
    for (int t = 0; t < 4; ++t) g2acc[t] = MFMA(a1, bA[4 + t], g2acc[t]);
  }
  // s3 = (g2pre>0)*V3 -> S2s; lyap partial
  float tot[4] = {0.f, 0.f, 0.f, 0.f};
  #pragma unroll
  for (int t = 0; t < 4; ++t) {
    int col = t * 16 + r;
    float c2v = c2[col], v3v = V3[col];
    #pragma unroll
    for (int g = 0; g < 4; ++g) {
      float pre = g2acc[t][g] + c2v;
      float g2 = pre > 0.f ? pre : 0.f;
      S2s[(w * 16 + q * 4 + g) * 72 + col] = pre > 0.f ? f2bf(v3v) : (u16)0;
      tot[g] += g2 * v3v;
    }
  }
  LDG8(bB, PV2n, (j & 3) * 2 + (j >> 2));
  LDS_FENCE();
  // s2 = s3 @ V2 (natural), masked by G1>0 -> S2s
  f32x4 s2acc[4] = {};
  {
    short8 a0 = *(const short8*)&S2s[arow * 72 + 0 + q * 8];
    short8 a1 = *(const short8*)&S2s[arow * 72 + 32 + q * 8];
    #pragma unroll
    for (int t = 0; t < 4; ++t) s2acc[t] = MFMA(a0, bB[t], s2acc[t]);
    #pragma unroll
    for (int t = 0; t < 4; ++t) s2acc[t] = MFMA(a1, bB[4 + t], s2acc[t]);
  }
  #pragma unroll
  for (int t = 0; t < 4; ++t) {
    int col = t * 16 + r;
    #pragma unroll
    for (int g = 0; g < 4; ++g) {
      float sv = g1v[t][g] > 0.f ? s2acc[t][g] : 0.f;
      S2s[(w * 16 + q * 4 + g) * 72 + col] = f2bf(sv);
    }
  }
  LDS_FENCE();
  float c3v = c3[0];
  float lyap_row[4];
  #pragma unroll
  for (int g = 0; g < 4; ++g) {
    float s = tot[g] + EPS_C * ssq[g];
    s += __shfl_xor(s, 1); s += __shfl_xor(s, 2); s += __shfl_xor(s, 4); s += __shfl_xor(s, 8);
    lyap_row[g] = s + c3v;
  }

  // all FP stores must land before same-address re-reads in phase C
  asm volatile("s_waitcnt vmcnt(0)" ::: "memory");

  // ================= phase C: U = s2 @ V1^T + 2eps*F; T3 accum = U @ W3^T =================
  f32x4 t3acc[4] = {};
  short8 s2a0 = *(const short8*)&S2s[arow * 72 + 0 + q * 8];
  short8 s2a1 = *(const short8*)&S2s[arow * 72 + 32 + q * 8];
  LDG8(bA, PV1n, (((j & 3)) * 2 + (j >> 2)));                    // V1n nc0 t0-3
  #pragma unroll 1
  for (int nc = 0; nc < 4; ++nc) {
    LDG8(bB, PV1n, ((nc * 8 + 4 + (j & 3)) * 2 + (j >> 2)));     // t4-7
    short4v fpr[8];
    #pragma unroll
    for (int t = 0; t < 8; ++t)
      fpr[t] = *(const short4v*)&FP[(size_t)(((strip * 4 + nc) * 8 + t) * 64 + lane) * 4];
    f32x4 uacc[8] = {};
    #pragma unroll
    for (int t = 0; t < 4; ++t) uacc[t] = MFMA(s2a0, bA[t], uacc[t]);
    #pragma unroll
    for (int t = 0; t < 4; ++t) uacc[t] = MFMA(s2a1, bA[4 + t], uacc[t]);
    LDG8(bA, PW3n, ((j & 3) * 16 + nc * 4 + (j >> 2)));          // W3n ks0,1
    #pragma unroll
    for (int t = 0; t < 4; ++t) uacc[4 + t] = MFMA(s2a0, bB[t], uacc[4 + t]);
    #pragma unroll
    for (int t = 0; t < 4; ++t) uacc[4 + t] = MFMA(s2a1, bB[4 + t], uacc[4 + t]);
    LDG8(bB, PW3n, ((j & 3) * 16 + nc * 4 + 2 + (j >> 2)));      // W3n ks2,3
    #pragma unroll
    for (int t = 0; t < 8; ++t) {
      #pragma unroll
      for (int g = 0; g < 4; ++g) {
        As[(w * 16 + q * 4 + g) * 136 + t * 16 + r] =
            f2bf(uacc[t][g] + 2.f * EPS_C * bf2f((u16)fpr[t][g]));
      }
    }
    LDS_FENCE();
    short8 a0 = *(const short8*)&As[arow * 136 + 0 * 32 + q * 8];
    short8 a1 = *(const short8*)&As[arow * 136 + 1 * 32 + q * 8];
    #pragma unroll
    for (int t = 0; t < 4; ++t) t3acc[t] = MFMA(a0, bA[t], t3acc[t]);
    #pragma unroll
    for (int t = 0; t < 4; ++t) t3acc[t] = MFMA(a1, bA[4 + t], t3acc[t]);
    int ncn = (nc + 1) & 3;
    LDG8(bA, PV1n, ((ncn * 8 + (j & 3)) * 2 + (j >> 2)));        // next t0-3
    short8 a2 = *(const short8*)&As[arow * 136 + 2 * 32 + q * 8];
    short8 a3 = *(const short8*)&As[arow * 136 + 3 * 32 + q * 8];
    #pragma unroll
    for (int t = 0; t < 4; ++t) t3acc[t] = MFMA(a2, bB[t], t3acc[t]);
    #pragma unroll
    for (int t = 0; t < 4; ++t) t3acc[t] = MFMA(a3, bB[4 + t], t3acc[t]);
    LDS_FENCE();
  }
  // T3 masked by H2>0 -> H2s
  #pragma unroll
  for (int t = 0; t < 4; ++t) {
    int col = t * 16 + r;
    #pragma unroll
    for (int g = 0; g < 4; ++g) {
      int addr = (w * 16 + q * 4 + g) * 72 + col;
      u16 h2 = H2s[addr];
      H2s[addr] = h2 ? f2bf(t3acc[t][g]) : (u16)0;
    }
  }
  LDG8(bB, PW2n, (j & 3) * 2 + (j >> 2));
  LDS_FENCE();
  // T2 = T3 @ W2 (natural), masked by H1>0 -> H1s
  f32x4 t2acc[4] = {};
  {
    short8 a0 = *(const short8*)&H2s[arow * 72 + 0 + q * 8];
    short8 a1 = *(const short8*)&H2s[arow * 72 + 32 + q * 8];
    #pragma unroll
    for (int t = 0; t < 4; ++t) t2acc[t] = MFMA(a0, bB[t], t2acc[t]);
    #pragma unroll
    for (int t = 0; t < 4; ++t) t2acc[t] = MFMA(a1, bB[4 + t], t2acc[t]);
  }
  #pragma unroll
  for (int t = 0; t < 4; ++t) {
    int col = t * 16 + r;
    #pragma unroll
    for (int g = 0; g < 4; ++g) {
      int addr = (w * 16 + q * 4 + g) * 72 + col;
      u16 h1 = H1s[addr];
      H1s[addr] = h1 ? f2bf(t2acc[t][g]) : (u16)0;
    }
  }
  LDG8(bA, PW1n, ((j >> 1) * 2 + (j & 1)));                      // GV nc0 t0-3 (j=t*2+ks)
  LDS_FENCE();
  short8 v0 = *(const short8*)&H1s[arow * 72 + 0 + q * 8];
  short8 v1 = *(const short8*)&H1s[arow * 72 + 32 + q * 8];
  *(short8*)&T2P[(size_t)((strip * 2 + 0) * 64 + lane) * 8] = v0;
  *(short8*)&T2P[(size_t)((strip * 2 + 1) * 64 + lane) * 8] = v1;
  // GV = T2 @ W1^T, row norms only
  float ssq2[4] = {0.f, 0.f, 0.f, 0.f};
  #pragma unroll 1
  for (int nc = 0; nc < 4; ++nc) {
    LDG8(bB, PW1n, ((nc * 8 + 4 + (j >> 1)) * 2 + (j & 1)));     // t4-7
    f32x4 acc[8] = {};
    #pragma unroll
    for (int t = 0; t < 4; ++t) {
      acc[t] = MFMA(v0, bA[t * 2 + 0], acc[t]);
      acc[t] = MFMA(v1, bA[t * 2 + 1], acc[t]);
    }
    int ncn = (nc + 1) & 3;
    LDG8(bA, PW1n, ((ncn * 8 + (j >> 1)) * 2 + (j & 1)));        // next t0-3
    #pragma unroll
    for (int t = 0; t < 4; ++t) {
      acc[4 + t] = MFMA(v0, bB[t * 2 + 0], acc[4 + t]);
      acc[4 + t] = MFMA(v1, bB[t * 2 + 1], acc[4 + t]);
    }
    #pragma unroll
    for (int t = 0; t < 8; ++t)
      #pragma unroll
      for (int g = 0; g < 4; ++g) ssq2[g] += acc[t][g] * acc[t][g];
  }
  float totw = 0.f;
  #pragma unroll
  for (int g = 0; g < 4; ++g) {
    float s = ssq2[g];
    s += __shfl_xor(s, 1); s += __shfl_xor(s, 2); s += __shfl_xor(s, 4); s += __shfl_xor(s, 8);
    if (r == 0) {
      int rowg = m0 + w * 16 + q * 4 + g;
      float nm = s + ALPHA_C * lyap_row[g];
      NUM[rowg] = nm > 0.f ? nm : 0.f;
    }
    s += __shfl_xor(s, 16); s += __shfl_xor(s, 32);
    totw += s;
  }
  if (lane == 0) dred[w] = totw;
  __syncthreads();
  if (tid == 0) atomicAdd(&DP[blockIdx.x & 255], dred[0] + dred[1] + dred[2] + dred[3]);
}

// ---------------------------------------------------------------------------
// K2: recompute GV from packed T2; out = F - (num/denom)*GV.
// Output transposed through LDS so global stores are 512B-contiguous float4.
__global__ __launch_bounds__(256, 2) void k_out(
    const u16* __restrict__ T2P, const u16* __restrict__ PW1n,
    const u16* __restrict__ FP, const float* __restrict__ NUM, const float* __restrict__ DP,
    float* __restrict__ out) {
  __shared__ float red[256];
  __shared__ float OutS[64 * 132];
  const int tid = threadIdx.x;
  const int lane = tid & 63, w = tid >> 6, q = lane >> 4, r = lane & 15;
  const int m0 = blockIdx.x * 64;
  const int strip = blockIdx.x * 4 + w;
  red[tid] = DP[tid];
  __syncthreads();
  for (int s = 128; s >= 1; s >>= 1) {
    if (tid < s) red[tid] += red[tid + s];
    __syncthreads();
  }
  const float inv_denom = 1.f / red[0];
  float sc[4];
  #pragma unroll
  for (int g = 0; g < 4; ++g) sc[g] = NUM[m0 + w * 16 + q * 4 + g] * inv_denom;
  short8 a0 = *(const short8*)&T2P[(size_t)((strip * 2 + 0) * 64 + lane) * 8];
  short8 a1 = *(const short8*)&T2P[(size_t)((strip * 2 + 1) * 64 + lane) * 8];
  short8 bA[8], bB[8];
  LDG8(bA, PW1n, ((j >> 1) * 2 + (j & 1)));                      // nc0 t0-3
  #pragma unroll 1
  for (int nc = 0; nc < 4; ++nc) {
    LDG8(bB, PW1n, ((nc * 8 + 4 + (j >> 1)) * 2 + (j & 1)));     // t4-7
    short4v fpr[8];
    #pragma unroll
    for (int t = 0; t < 8; ++t)
      fpr[t] = *(const short4v*)&FP[(size_t)(((strip * 4 + nc) * 8 + t) * 64 + lane) * 4];
    f32x4 acc[8] = {};
    #pragma unroll
    for (int t = 0; t < 4; ++t) {
      acc[t] = MFMA(a0, bA[t * 2 + 0], acc[t]);
      acc[t] = MFMA(a1, bA[t * 2 + 1], acc[t]);
    }
    int ncn = (nc + 1) & 3;
    LDG8(bA, PW1n, ((ncn * 8 + (j >> 1)) * 2 + (j & 1)));        // next t0-3
    #pragma unroll
    for (int t = 0; t < 4; ++t) {
      acc[4 + t] = MFMA(a0, bB[t * 2 + 0], acc[4 + t]);
      acc[4 + t] = MFMA(a1, bB[t * 2 + 1], acc[4 + t]);
    }
    #pragma unroll
    for (int t = 0; t < 8; ++t) {
      #pragma unroll
      for (int g = 0; g < 4; ++g)
        OutS[(w * 16 + q * 4 + g) * 132 + t * 16 + r] =
            bf2f((u16)fpr[t][g]) - sc[g] * acc[t][g];
    }
    LDS_FENCE();
    #pragma unroll
    for (int jj = 0; jj < 8; ++jj) {
      f32x4 ov = *(const f32x4*)&OutS[(w * 16 + (lane >> 5) + jj * 2) * 132 + (lane & 31) * 4];
      *(f32x4*)&out[(size_t)(m0 + w * 16 + (lane >> 5) + jj * 2) * 512 + nc * 128 + (lane & 31) * 4] = ov;
    }
    LDS_FENCE();
  }
}

// ---------------------------------------------------------------------------
extern "C" void kernel_launch(void* const* d_in, const int* in_sizes, int n_in,
                              void* d_out, int out_size, void* d_ws, size_t ws_size,
                              hipStream_t stream) {
  const float* x  = (const float*)d_in[0];
  const float* W1 = (const float*)d_in[1];
  const float* b1 = (const float*)d_in[2];
  const float* W2 = (const float*)d_in[3];
  const float* b2 = (const float*)d_in[4];
  const float* W3 = (const float*)d_in[5];
  const float* b3 = (const float*)d_in[6];
  const float* V1 = (const float*)d_in[7];
  const float* c1 = (const float*)d_in[8];
  const float* V2 = (const float*)d_in[9];
  const float* c2 = (const float*)d_in[10];
  const float* V3 = (const float*)d_in[11];
  const float* c3 = (const float*)d_in[12];
  float* out = (float*)d_out;

  u16* FP = (u16*)d_ws;                        // 16777216 u16 = 32 MB
  float* NUM = (float*)(FP + 16777216);        // 32768 f
  float* DP  = NUM + 32768;                    // 256 f
  u16* T2P  = (u16*)(DP + 256);                // 2097152 u16
  u16* PW1T = T2P + 2097152;
  u16* PW1n = PW1T + 32768;
  u16* PV1T = PW1n + 32768;
  u16* PV1n = PV1T + 32768;
  u16* PW3T = PV1n + 32768;
  u16* PW3n = PW3T + 32768;
  u16* PW2T = PW3n + 32768;
  u16* PW2n = PW2T + 4096;
  u16* PV2T = PW2n + 4096;
  u16* PV2n = PV2T + 4096;

  k_conv<<<128, 256, 0, stream>>>(W1, W2, W3, V1, V2,
                                  PW1T, PW1n, PV1T, PV1n, PW3T, PW3n,
                                  PW2T, PW2n, PV2T, PV2n, DP);
  k_fused<<<512, 256, 0, stream>>>(x, PW1T, b1, PW2T, b2, PW3T, b3, PV1T, c1,
                                   PV2T, PV2n, c2, V3, c3, PV1n, PW3n, PW2n, PW1n,
                                   FP, T2P, NUM, DP);
  k_out<<<512, 256, 0, stream>>>(T2P, PW1n, FP, NUM, DP, out);
}

// Round 5
// 172.819 us; speedup vs baseline: 1.6213x; 1.0307x over previous
//
#include <hip/hip_runtime.h>

#define ALPHA_C 0.9f
#define EPS_C 1e-3f

typedef unsigned short u16;
typedef __attribute__((ext_vector_type(8))) short short8;
typedef __attribute__((ext_vector_type(4))) short short4v;
typedef __attribute__((ext_vector_type(4))) float f32x4;
#define MFMA(a, b, c) __builtin_amdgcn_mfma_f32_16x16x32_bf16(a, b, c, 0, 0, 0)
// compiler-only ordering fence; wave-private LDS hazards are in-order in HW
#define LDS_FENCE() asm volatile("" ::: "memory")
// raw barriers: do NOT drain vmcnt (in-flight global loads/stores survive)
#define BAR_TOP()    { LDS_FENCE(); __builtin_amdgcn_s_barrier(); LDS_FENCE(); }
#define BAR_STAGED() { LDS_FENCE(); asm volatile("s_waitcnt lgkmcnt(0)" ::: "memory"); \
                       __builtin_amdgcn_s_barrier(); LDS_FENCE(); }

__device__ __forceinline__ u16 f2bf(float f) {
  union { float f; unsigned u; } v; v.f = f;
  unsigned u = v.u;
  u += 0x7FFFu + ((u >> 16) & 1u);
  return (u16)(u >> 16);
}
__device__ __forceinline__ float bf2f(u16 h) {
  union { unsigned u; float f; } v; v.u = ((unsigned)h) << 16;
  return v.f;
}

// ---------------------------------------------------------------------------
// K0: weight conversion fp32 -> bf16, packed in MFMA B-fragment order.
__global__ __launch_bounds__(256) void k_conv(
    const float* __restrict__ W1, const float* __restrict__ W2, const float* __restrict__ W3,
    const float* __restrict__ V1, const float* __restrict__ V2,
    u16* __restrict__ PW1T, u16* __restrict__ PW1n, u16* __restrict__ PV1T, u16* __restrict__ PV1n,
    u16* __restrict__ PW3T, u16* __restrict__ PW3n, u16* __restrict__ PW2T, u16* __restrict__ PW2n,
    u16* __restrict__ PV2T, u16* __restrict__ PV2n, float* __restrict__ DP) {
  int i = blockIdx.x * 256 + threadIdx.x;   // 0..32767
  if (i < 256) DP[i] = 0.f;
  {
    int k = i >> 6, j = i & 63;             // W1[k][j], V1[k][j]  (512x64)
    u16 b = f2bf(W1[i]);
    PW1T[((((j >> 4) * 16 + (k >> 5)) * 4 + ((k & 31) >> 3)) * 16 + (j & 15)) * 8 + (k & 7)] = b;
    PW1n[((((k >> 4) * 2 + (j >> 5)) * 4 + ((j & 31) >> 3)) * 16 + (k & 15)) * 8 + (j & 7)] = b;
    u16 c = f2bf(V1[i]);
    PV1T[((((j >> 4) * 16 + (k >> 5)) * 4 + ((k & 31) >> 3)) * 16 + (j & 15)) * 8 + (k & 7)] = c;
    PV1n[((((k >> 4) * 2 + (j >> 5)) * 4 + ((j & 31) >> 3)) * 16 + (k & 15)) * 8 + (j & 7)] = c;
  }
  {
    int k = i >> 9, n = i & 511;            // W3[k][n] (64x512)
    u16 b = f2bf(W3[i]);
    PW3T[((((n >> 4) * 2 + (k >> 5)) * 4 + ((k & 31) >> 3)) * 16 + (n & 15)) * 8 + (k & 7)] = b;
    PW3n[((((k >> 4) * 16 + (n >> 5)) * 4 + ((n & 31) >> 3)) * 16 + (k & 15)) * 8 + (n & 7)] = b;
  }
  if (i < 4096) {
    int k = i >> 6, j = i & 63;             // W2[k][j], V2[k][j] (64x64)
    u16 b = f2bf(W2[i]);
    PW2T[((((j >> 4) * 2 + (k >> 5)) * 4 + ((k & 31) >> 3)) * 16 + (j & 15)) * 8 + (k & 7)] = b;
    PW2n[((((k >> 4) * 2 + (j >> 5)) * 4 + ((j & 31) >> 3)) * 16 + (k & 15)) * 8 + (j & 7)] = b;
    u16 c = f2bf(V2[i]);
    PV2T[((((j >> 4) * 2 + (k >> 5)) * 4 + ((k & 31) >> 3)) * 16 + (j & 15)) * 8 + (k & 7)] = c;
    PV2n[((((k >> 4) * 2 + (j >> 5)) * 4 + ((j & 31) >> 3)) * 16 + (k & 15)) * 8 + (j & 7)] = c;
  }
}

// helper: load 8 b-fragments from global (frag index expression in j) - used by k_out
#define LDG8(dst, P, FRAG)                                                      \
  _Pragma("unroll") for (int j = 0; j < 8; ++j)                                 \
    dst[j] = *(const short8*)&P[((size_t)(FRAG) * 64 + lane) * 8];

// stage 16 contiguous fragments (16KB) into Ws at local frag base DST
#define STAGE16(DST, P, SRCFRAG)                                                \
  _Pragma("unroll") for (int c = 0; c < 4; ++c)                                 \
    *(short8*)&Ws[((DST) * 512) + (c * 256 + tid) * 8] =                        \
      *(const short8*)&P[((size_t)(SRCFRAG) * 512) + (c * 256 + tid) * 8];

// stage 4 chunks of 4 fragments: chunk t from global frag (t*16 + OFF) to local (DST + t*4)
#define STAGE4x4(DST, P, OFF)                                                   \
  _Pragma("unroll") for (int t = 0; t < 4; ++t)                                 \
    *(short8*)&Ws[((DST) + t * 4) * 512 + tid * 8] =                            \
      *(const short8*)&P[((size_t)(t * 16 + (OFF))) * 512 + tid * 8];

// ---------------------------------------------------------------------------
__global__ __launch_bounds__(256, 2) void k_fused(
    const float* __restrict__ x,
    const u16* __restrict__ PW1T, const float* __restrict__ b1,
    const u16* __restrict__ PW2T, const float* __restrict__ b2,
    const u16* __restrict__ PW3T, const float* __restrict__ b3,
    const u16* __restrict__ PV1T, const float* __restrict__ c1,
    const u16* __restrict__ PV2T, const u16* __restrict__ PV2n, const float* __restrict__ c2,
    const float* __restrict__ V3, const float* __restrict__ c3,
    const u16* __restrict__ PV1n, const u16* __restrict__ PW3n,
    const u16* __restrict__ PW2n, const u16* __restrict__ PW1n,
    u16* __restrict__ FP, u16* __restrict__ T2P,
    float* __restrict__ NUM, float* __restrict__ DP) {
  __shared__ __align__(16) u16 H1s[64 * 72];
  __shared__ __align__(16) u16 H2s[64 * 72];
  __shared__ __align__(16) u16 S2s[64 * 72];
  __shared__ __align__(16) u16 As[64 * 136];
  __shared__ __align__(16) u16 Ws[16384];    // 32 KB shared weight window
  __shared__ float dred[4];
  const int tid = threadIdx.x;
  const int lane = tid & 63, w = tid >> 6, q = lane >> 4, r = lane & 15;
  const int m0 = blockIdx.x * 64;
  const int arow = w * 16 + r;
  const int strip = blockIdx.x * 4 + w;
  const int h = lane >> 5, c4 = lane & 31;
  const float* xbase = x + (size_t)(m0 + w * 16) * 512;

  // ================= phase A1: H1 = relu(x @ W1 + b1) =================
  f32x4 acc1[4] = {};
  float4 xr[8];
  #pragma unroll
  for (int it = 0; it < 8; ++it)
    xr[it] = *(const float4*)&xbase[(it * 2 + h) * 512 + c4 * 4];
  #pragma unroll 1
  for (int kc = 0; kc < 4; ++kc) {
    BAR_TOP();                               // Ws free for reuse
    STAGE4x4(0, PW1T, kc * 4);               // local frag t*4+ks
    #pragma unroll
    for (int it = 0; it < 8; ++it) {         // x -> As (wave-private rows)
      float4 v = xr[it]; short4v s4;
      s4[0] = (short)f2bf(v.x); s4[1] = (short)f2bf(v.y);
      s4[2] = (short)f2bf(v.z); s4[3] = (short)f2bf(v.w);
      *(short4v*)&As[(w * 16 + it * 2 + h) * 136 + c4 * 4] = s4;
    }
    if (kc < 3) {
      #pragma unroll
      for (int it = 0; it < 8; ++it)
        xr[it] = *(const float4*)&xbase[(it * 2 + h) * 512 + (kc + 1) * 128 + c4 * 4];
    }
    BAR_STAGED();                            // Ws (and As) visible
    #pragma unroll
    for (int ks = 0; ks < 4; ++ks) {
      short8 a = *(const short8*)&As[arow * 136 + ks * 32 + q * 8];
      #pragma unroll
      for (int t = 0; t < 4; ++t) {
        short8 b = *(const short8*)&Ws[((t * 4 + ks) * 64 + lane) * 8];
        acc1[t] = MFMA(a, b, acc1[t]);
      }
    }
  }
  #pragma unroll
  for (int t = 0; t < 4; ++t) {
    int col = t * 16 + r; float bv = b1[col];
    #pragma unroll
    for (int g = 0; g < 4; ++g) {
      float hh = acc1[t][g] + bv; hh = hh > 0.f ? hh : 0.f;
      H1s[(w * 16 + q * 4 + g) * 72 + col] = f2bf(hh);
    }
  }
  LDS_FENCE();

  // ================= phase A2: H2 = relu(H1 @ W2 + b2)  [direct, 8 KB] =================
  {
    short8 a0 = *(const short8*)&H1s[arow * 72 + 0 + q * 8];
    short8 a1 = *(const short8*)&H1s[arow * 72 + 32 + q * 8];
    f32x4 acc2[4] = {};
    #pragma unroll
    for (int t = 0; t < 4; ++t) {
      short8 b0 = *(const short8*)&PW2T[((t * 2 + 0) * 64 + lane) * 8];
      short8 b1 = *(const short8*)&PW2T[((t * 2 + 1) * 64 + lane) * 8];
      acc2[t] = MFMA(a0, b0, acc2[t]);
      acc2[t] = MFMA(a1, b1, acc2[t]);
    }
    #pragma unroll
    for (int t = 0; t < 4; ++t) {
      int col = t * 16 + r; float bv = b2[col];
      #pragma unroll
      for (int g = 0; g < 4; ++g) {
        float hh = acc2[t][g] + bv; hh = hh > 0.f ? hh : 0.f;
        H2s[(w * 16 + q * 4 + g) * 72 + col] = f2bf(hh);
      }
    }
  }
  LDS_FENCE();

  // ================= phase B: F = H2 @ W3 + b3; G1 accum = F @ V1 =================
  f32x4 g1acc[4] = {};
  float ssq[4] = {0.f, 0.f, 0.f, 0.f};
  short8 h2a0 = *(const short8*)&H2s[arow * 72 + 0 + q * 8];
  short8 h2a1 = *(const short8*)&H2s[arow * 72 + 32 + q * 8];
  #pragma unroll 1
  for (int nc = 0; nc < 4; ++nc) {
    BAR_TOP();
    STAGE16(0, PW3T, nc * 16);               // local frag t*2+ks   (t<8)
    STAGE4x4(16, PV1T, nc * 4);              // local frag 16+t*4+ks (t<4)
    BAR_STAGED();
    f32x4 facc[8] = {};
    #pragma unroll
    for (int t = 0; t < 8; ++t) {
      short8 b0 = *(const short8*)&Ws[((t * 2 + 0) * 64 + lane) * 8];
      short8 b1 = *(const short8*)&Ws[((t * 2 + 1) * 64 + lane) * 8];
      facc[t] = MFMA(h2a0, b0, facc[t]);
      facc[t] = MFMA(h2a1, b1, facc[t]);
    }
    #pragma unroll
    for (int t = 0; t < 8; ++t) {
      float bv = b3[nc * 128 + t * 16 + r];
      short4v s4;
      #pragma unroll
      for (int g = 0; g < 4; ++g) {
        float v = facc[t][g] + bv;
        ssq[g] += v * v;
        u16 bb = f2bf(v);
        As[(w * 16 + q * 4 + g) * 136 + t * 16 + r] = bb;
        s4[g] = (short)bb;
      }
      *(short4v*)&FP[(size_t)(((strip * 4 + nc) * 8 + t) * 64 + lane) * 4] = s4;
    }
    LDS_FENCE();
    #pragma unroll
    for (int ks = 0; ks < 4; ++ks) {
      short8 a = *(const short8*)&As[arow * 136 + ks * 32 + q * 8];
      #pragma unroll
      for (int t = 0; t < 4; ++t) {
        short8 b = *(const short8*)&Ws[((16 + t * 4 + ks) * 64 + lane) * 8];
        g1acc[t] = MFMA(a, b, g1acc[t]);
      }
    }
  }

  // G1 = relu(g1acc + c1) -> S2s
  f32x4 g1v[4];
  #pragma unroll
  for (int t = 0; t < 4; ++t) {
    int col = t * 16 + r; float cv = c1[col];
    #pragma unroll
    for (int g = 0; g < 4; ++g) {
      float v = g1acc[t][g] + cv; v = v > 0.f ? v : 0.f;
      g1v[t][g] = v;
      S2s[(w * 16 + q * 4 + g) * 72 + col] = f2bf(v);
    }
  }
  LDS_FENCE();
  // g2 = G1 @ V2T  [direct, 8 KB]
  f32x4 g2acc[4] = {};
  {
    short8 a0 = *(const short8*)&S2s[arow * 72 + 0 + q * 8];
    short8 a1 = *(const short8*)&S2s[arow * 72 + 32 + q * 8];
    #pragma unroll
    for (int t = 0; t < 4; ++t) {
      short8 b0 = *(const short8*)&PV2T[((t * 2 + 0) * 64 + lane) * 8];
      short8 b1 = *(const short8*)&PV2T[((t * 2 + 1) * 64 + lane) * 8];
      g2acc[t] = MFMA(a0, b0, g2acc[t]);
      g2acc[t] = MFMA(a1, b1, g2acc[t]);
    }
  }
  // s3 = (g2pre>0)*V3 -> S2s; lyap partial
  float tot[4] = {0.f, 0.f, 0.f, 0.f};
  #pragma unroll
  for (int t = 0; t < 4; ++t) {
    int col = t * 16 + r;
    float c2v = c2[col], v3v = V3[col];
    #pragma unroll
    for (int g = 0; g < 4; ++g) {
      float pre = g2acc[t][g] + c2v;
      float g2 = pre > 0.f ? pre : 0.f;
      S2s[(w * 16 + q * 4 + g) * 72 + col] = pre > 0.f ? f2bf(v3v) : (u16)0;
      tot[g] += g2 * v3v;
    }
  }
  LDS_FENCE();
  // s2 = s3 @ V2 (natural), masked by G1>0 -> S2s  [direct, 8 KB]
  f32x4 s2acc[4] = {};
  {
    short8 a0 = *(const short8*)&S2s[arow * 72 + 0 + q * 8];
    short8 a1 = *(const short8*)&S2s[arow * 72 + 32 + q * 8];
    #pragma unroll
    for (int t = 0; t < 4; ++t) {
      short8 b0 = *(const short8*)&PV2n[((t * 2 + 0) * 64 + lane) * 8];
      short8 b1 = *(const short8*)&PV2n[((t * 2 + 1) * 64 + lane) * 8];
      s2acc[t] = MFMA(a0, b0, s2acc[t]);
      s2acc[t] = MFMA(a1, b1, s2acc[t]);
    }
  }
  #pragma unroll
  for (int t = 0; t < 4; ++t) {
    int col = t * 16 + r;
    #pragma unroll
    for (int g = 0; g < 4; ++g) {
      float sv = g1v[t][g] > 0.f ? s2acc[t][g] : 0.f;
      S2s[(w * 16 + q * 4 + g) * 72 + col] = f2bf(sv);
    }
  }
  LDS_FENCE();
  float c3v = c3[0];
  float lyap_row[4];
  #pragma unroll
  for (int g = 0; g < 4; ++g) {
    float s = tot[g] + EPS_C * ssq[g];
    s += __shfl_xor(s, 1); s += __shfl_xor(s, 2); s += __shfl_xor(s, 4); s += __shfl_xor(s, 8);
    lyap_row[g] = s + c3v;
  }

  // all FP stores must land before same-address re-reads in phase C
  asm volatile("s_waitcnt vmcnt(0)" ::: "memory");

  // ================= phase C: U = s2 @ V1^T + 2eps*F; T3 accum = U @ W3^T =================
  f32x4 t3acc[4] = {};
  short8 s2a0 = *(const short8*)&S2s[arow * 72 + 0 + q * 8];
  short8 s2a1 = *(const short8*)&S2s[arow * 72 + 32 + q * 8];
  #pragma unroll 1
  for (int nc = 0; nc < 4; ++nc) {
    BAR_TOP();
    STAGE16(0, PV1n, nc * 16);               // local frag t*2+ks (t<8)
    STAGE4x4(16, PW3n, nc * 4);              // local frag 16+t*4+ks
    BAR_STAGED();
    short4v fpr[8];
    #pragma unroll
    for (int t = 0; t < 8; ++t)
      fpr[t] = *(const short4v*)&FP[(size_t)(((strip * 4 + nc) * 8 + t) * 64 + lane) * 4];
    f32x4 uacc[8] = {};
    #pragma unroll
    for (int t = 0; t < 8; ++t) {
      short8 b0 = *(const short8*)&Ws[((t * 2 + 0) * 64 + lane) * 8];
      short8 b1 = *(const short8*)&Ws[((t * 2 + 1) * 64 + lane) * 8];
      uacc[t] = MFMA(s2a0, b0, uacc[t]);
      uacc[t] = MFMA(s2a1, b1, uacc[t]);
    }
    #pragma unroll
    for (int t = 0; t < 8; ++t) {
      #pragma unroll
      for (int g = 0; g < 4; ++g) {
        As[(w * 16 + q * 4 + g) * 136 + t * 16 + r] =
            f2bf(uacc[t][g] + 2.f * EPS_C * bf2f((u16)fpr[t][g]));
      }
    }
    LDS_FENCE();
    #pragma unroll
    for (int ks = 0; ks < 4; ++ks) {
      short8 a = *(const short8*)&As[arow * 136 + ks * 32 + q * 8];
      #pragma unroll
      for (int t = 0; t < 4; ++t) {
        short8 b = *(const short8*)&Ws[((16 + t * 4 + ks) * 64 + lane) * 8];
        t3acc[t] = MFMA(a, b, t3acc[t]);
      }
    }
  }
  // T3 masked by H2>0 -> H2s
  #pragma unroll
  for (int t = 0; t < 4; ++t) {
    int col = t * 16 + r;
    #pragma unroll
    for (int g = 0; g < 4; ++g) {
      int addr = (w * 16 + q * 4 + g) * 72 + col;
      u16 h2 = H2s[addr];
      H2s[addr] = h2 ? f2bf(t3acc[t][g]) : (u16)0;
    }
  }
  LDS_FENCE();
  // T2 = T3 @ W2 (natural), masked by H1>0 -> H1s  [direct, 8 KB]
  f32x4 t2acc[4] = {};
  {
    short8 a0 = *(const short8*)&H2s[arow * 72 + 0 + q * 8];
    short8 a1 = *(const short8*)&H2s[arow * 72 + 32 + q * 8];
    #pragma unroll
    for (int t = 0; t < 4; ++t) {
      short8 b0 = *(const short8*)&PW2n[((t * 2 + 0) * 64 + lane) * 8];
      short8 b1 = *(const short8*)&PW2n[((t * 2 + 1) * 64 + lane) * 8];
      t2acc[t] = MFMA(a0, b0, t2acc[t]);
      t2acc[t] = MFMA(a1, b1, t2acc[t]);
    }
  }
  #pragma unroll
  for (int t = 0; t < 4; ++t) {
    int col = t * 16 + r;
    #pragma unroll
    for (int g = 0; g < 4; ++g) {
      int addr = (w * 16 + q * 4 + g) * 72 + col;
      u16 h1 = H1s[addr];
      H1s[addr] = h1 ? f2bf(t2acc[t][g]) : (u16)0;
    }
  }
  LDS_FENCE();
  // T2 A-fragments -> packed global (coalesced), reused for GV
  short8 v0 = *(const short8*)&H1s[arow * 72 + 0 + q * 8];
  short8 v1 = *(const short8*)&H1s[arow * 72 + 32 + q * 8];
  *(short8*)&T2P[(size_t)((strip * 2 + 0) * 64 + lane) * 8] = v0;
  *(short8*)&T2P[(size_t)((strip * 2 + 1) * 64 + lane) * 8] = v1;
  // GV = T2 @ W1^T, row norms only
  float ssq2[4] = {0.f, 0.f, 0.f, 0.f};
  #pragma unroll 1
  for (int nc = 0; nc < 4; ++nc) {
    BAR_TOP();
    STAGE16(0, PW1n, nc * 16);               // local frag t*2+ks (t<8)
    BAR_STAGED();
    f32x4 acc[8] = {};
    #pragma unroll
    for (int t = 0; t < 8; ++t) {
      short8 b0 = *(const short8*)&Ws[((t * 2 + 0) * 64 + lane) * 8];
      short8 b1 = *(const short8*)&Ws[((t * 2 + 1) * 64 + lane) * 8];
      acc[t] = MFMA(v0, b0, acc[t]);
      acc[t] = MFMA(v1, b1, acc[t]);
    }
    #pragma unroll
    for (int t = 0; t < 8; ++t)
      #pragma unroll
      for (int g = 0; g < 4; ++g) ssq2[g] += acc[t][g] * acc[t][g];
  }
  float totw = 0.f;
  #pragma unroll
  for (int g = 0; g < 4; ++g) {
    float s = ssq2[g];
    s += __shfl_xor(s, 1); s += __shfl_xor(s, 2); s += __shfl_xor(s, 4); s += __shfl_xor(s, 8);
    if (r == 0) {
      int rowg = m0 + w * 16 + q * 4 + g;
      float nm = s + ALPHA_C * lyap_row[g];
      NUM[rowg] = nm > 0.f ? nm : 0.f;
    }
    s += __shfl_xor(s, 16); s += __shfl_xor(s, 32);
    totw += s;
  }
  if (lane == 0) dred[w] = totw;
  __syncthreads();
  if (tid == 0) atomicAdd(&DP[blockIdx.x & 255], dred[0] + dred[1] + dred[2] + dred[3]);
}

// ---------------------------------------------------------------------------
// K2: recompute GV from packed T2; out = F - (num/denom)*GV.
// Output transposed through LDS so global stores are 512B-contiguous float4.
__global__ __launch_bounds__(256, 2) void k_out(
    const u16* __restrict__ T2P, const u16* __restrict__ PW1n,
    const u16* __restrict__ FP, const float* __restrict__ NUM, const float* __restrict__ DP,
    float* __restrict__ out) {
  __shared__ float red[256];
  __shared__ __align__(16) float OutS[64 * 132];
  const int tid = threadIdx.x;
  const int lane = tid & 63, w = tid >> 6, q = lane >> 4, r = lane & 15;
  const int m0 = blockIdx.x * 64;
  const int strip = blockIdx.x * 4 + w;
  red[tid] = DP[tid];
  __syncthreads();
  for (int s = 128; s >= 1; s >>= 1) {
    if (tid < s) red[tid] += red[tid + s];
    __syncthreads();
  }
  const float inv_denom = 1.f / red[0];
  float sc[4];
  #pragma unroll
  for (int g = 0; g < 4; ++g) sc[g] = NUM[m0 + w * 16 + q * 4 + g] * inv_denom;
  short8 a0 = *(const short8*)&T2P[(size_t)((strip * 2 + 0) * 64 + lane) * 8];
  short8 a1 = *(const short8*)&T2P[(size_t)((strip * 2 + 1) * 64 + lane) * 8];
  short8 bA[8], bB[8];
  LDG8(bA, PW1n, ((j >> 1) * 2 + (j & 1)));                      // nc0 t0-3
  #pragma unroll 1
  for (int nc = 0; nc < 4; ++nc) {
    LDG8(bB, PW1n, ((nc * 8 + 4 + (j >> 1)) * 2 + (j & 1)));     // t4-7
    short4v fpr[8];
    #pragma unroll
    for (int t = 0; t < 8; ++t)
      fpr[t] = *(const short4v*)&FP[(size_t)(((strip * 4 + nc) * 8 + t) * 64 + lane) * 4];
    f32x4 acc[8] = {};
    #pragma unroll
    for (int t = 0; t < 4; ++t) {
      acc[t] = MFMA(a0, bA[t * 2 + 0], acc[t]);
      acc[t] = MFMA(a1, bA[t * 2 + 1], acc[t]);
    }
    int ncn = (nc + 1) & 3;
    LDG8(bA, PW1n, ((ncn * 8 + (j >> 1)) * 2 + (j & 1)));        // next t0-3
    #pragma unroll
    for (int t = 0; t < 4; ++t) {
      acc[4 + t] = MFMA(a0, bB[t * 2 + 0], acc[4 + t]);
      acc[4 + t] = MFMA(a1, bB[t * 2 + 1], acc[4 + t]);
    }
    #pragma unroll
    for (int t = 0; t < 8; ++t) {
      #pragma unroll
      for (int g = 0; g < 4; ++g)
        OutS[(w * 16 + q * 4 + g) * 132 + t * 16 + r] =
            bf2f((u16)fpr[t][g]) - sc[g] * acc[t][g];
    }
    LDS_FENCE();
    #pragma unroll
    for (int jj = 0; jj < 8; ++jj) {
      f32x4 ov = *(const f32x4*)&OutS[(w * 16 + (lane >> 5) + jj * 2) * 132 + (lane & 31) * 4];
      *(f32x4*)&out[(size_t)(m0 + w * 16 + (lane >> 5) + jj * 2) * 512 + nc * 128 + (lane & 31) * 4] = ov;
    }
    LDS_FENCE();
  }
}

// ---------------------------------------------------------------------------
extern "C" void kernel_launch(void* const* d_in, const int* in_sizes, int n_in,
                              void* d_out, int out_size, void* d_ws, size_t ws_size,
                              hipStream_t stream) {
  const float* x  = (const float*)d_in[0];
  const float* W1 = (const float*)d_in[1];
  const float* b1 = (const float*)d_in[2];
  const float* W2 = (const float*)d_in[3];
  const float* b2 = (const float*)d_in[4];
  const float* W3 = (const float*)d_in[5];
  const float* b3 = (const float*)d_in[6];
  const float* V1 = (const float*)d_in[7];
  const float* c1 = (const float*)d_in[8];
  const float* V2 = (const float*)d_in[9];
  const float* c2 = (const float*)d_in[10];
  const float* V3 = (const float*)d_in[11];
  const float* c3 = (const float*)d_in[12];
  float* out = (float*)d_out;

  u16* FP = (u16*)d_ws;                        // 16777216 u16 = 32 MB
  float* NUM = (float*)(FP + 16777216);        // 32768 f
  float* DP  = NUM + 32768;                    // 256 f
  u16* T2P  = (u16*)(DP + 256);                // 2097152 u16
  u16* PW1T = T2P + 2097152;
  u16* PW1n = PW1T + 32768;
  u16* PV1T = PW1n + 32768;
  u16* PV1n = PV1T + 32768;
  u16* PW3T = PV1n + 32768;
  u16* PW3n = PW3T + 32768;
  u16* PW2T = PW3n + 32768;
  u16* PW2n = PW2T + 4096;
  u16* PV2T = PW2n + 4096;
  u16* PV2n = PV2T + 4096;

  k_conv<<<128, 256, 0, stream>>>(W1, W2, W3, V1, V2,
                                  PW1T, PW1n, PV1T, PV1n, PW3T, PW3n,
                                  PW2T, PW2n, PV2T, PV2n, DP);
  k_fused<<<512, 256, 0, stream>>>(x, PW1T, b1, PW2T, b2, PW3T, b3, PV1T, c1,
                                   PV2T, PV2n, c2, V3, c3, PV1n, PW3n, PW2n, PW1n,
                                   FP, T2P, NUM, DP);
  k_out<<<512, 256, 0, stream>>>(T2P, PW1n, FP, NUM, DP, out);
}